// Round 15
// baseline (527.059 us; speedup 1.0000x reference)
//
#include <hip/hip_runtime.h>
#include <hip/hip_bf16.h>
#include <hip/hip_fp16.h>
#include <math.h>

// ---------------------------------------------------------------------------
// A3T-GCN two-layer, restructured (see round-1 notes):
//   - H == 0 => R gate dead, cell = (1-Z)*tanh(...)
//   - A_hat commutes with W => one propagation per layer, folded gate matrices
//   - layer2 time channel reuses layer-1 propagation (rank-1 per period)
// Round 15: agg2 per-wave work-stealing (chunks of 2 nodes, 8 partition
// counters keyed by blockIdx&7) to remove the static-assignment ramp-down
// tail (occupancy 60% at a capacity launch). Grid stays 1024 = one
// generation. Rest identical to round 14.
// ---------------------------------------------------------------------------

typedef float f4v __attribute__((ext_vector_type(4)));
typedef unsigned u2v __attribute__((ext_vector_type(2)));

static __device__ __forceinline__ unsigned short f2bf(float f) {
    unsigned u = __float_as_uint(f);
    unsigned r = (u + 0x7FFFu + ((u >> 16) & 1u)) >> 16;  // RNE
    return (unsigned short)r;
}
static __device__ __forceinline__ float bf2f(unsigned short u) {
    return __uint_as_float(((unsigned)u) << 16);
}
static __device__ __forceinline__ unsigned short f2h(float f) {
    __half h = __float2half_rn(f);
    return *reinterpret_cast<unsigned short*>(&h);
}
static __device__ __forceinline__ float h2f(unsigned short u) {
    __half h;
    *reinterpret_cast<unsigned short*>(&h) = u;
    return __half2float(h);
}

// blocks [0, ncb): convert x1 -> padded bf16 rows [N][32] (ch>=24 zero).
// blocks [ncb, ...): count edges, emitting CSR slot epos[e] from the atomic.
__global__ void cvt_count(const float* __restrict__ in, unsigned short* __restrict__ outh,
                          int n32, int ncb,
                          const int* __restrict__ dst, int* __restrict__ cnt,
                          int* __restrict__ epos, int E) {
    if ((int)blockIdx.x < ncb) {
        int i = (blockIdx.x * blockDim.x + threadIdx.x) * 4;
        if (i < n32) {
            int node = i >> 5, c = i & 31;
            const float* row = in + (size_t)node * 24;
            ushort4 u;
            u.x = (c + 0 < 24) ? f2bf(__builtin_nontemporal_load(row + c + 0)) : (unsigned short)0;
            u.y = (c + 1 < 24) ? f2bf(__builtin_nontemporal_load(row + c + 1)) : (unsigned short)0;
            u.z = (c + 2 < 24) ? f2bf(__builtin_nontemporal_load(row + c + 2)) : (unsigned short)0;
            u.w = (c + 3 < 24) ? f2bf(__builtin_nontemporal_load(row + c + 3)) : (unsigned short)0;
            *(ushort4*)(outh + i) = u;
        }
    } else {
        int e = (blockIdx.x - ncb) * blockDim.x + threadIdx.x;
        if (e < E) {
            int d = __builtin_nontemporal_load(dst + e);
            int pos = atomicAdd(&cnt[d], 1);
            __builtin_nontemporal_store(pos, epos + e);
        }
    }
}

// --- parallel exclusive scan of cnt -> rowptr, plus dinv ------------------
__global__ __launch_bounds__(256) void scan_blocksum(
    const int* __restrict__ cnt, float* __restrict__ dinv,
    int* __restrict__ bsum, int n) {
    int base = blockIdx.x * 1024 + threadIdx.x * 4;
    int s = 0;
    if (base + 3 < n) {
        int4 v = *(const int4*)(cnt + base);
        dinv[base + 0] = rsqrtf((float)v.x + 1.f);
        dinv[base + 1] = rsqrtf((float)v.y + 1.f);
        dinv[base + 2] = rsqrtf((float)v.z + 1.f);
        dinv[base + 3] = rsqrtf((float)v.w + 1.f);
        s = v.x + v.y + v.z + v.w;
    } else {
        for (int k = 0; k < 4; ++k)
            if (base + k < n) {
                int v = cnt[base + k];
                dinv[base + k] = rsqrtf((float)v + 1.f);
                s += v;
            }
    }
    #pragma unroll
    for (int off = 32; off > 0; off >>= 1) s += __shfl_down(s, off, 64);
    __shared__ int ws[4];
    int lane = threadIdx.x & 63, wid = threadIdx.x >> 6;
    if (lane == 0) ws[wid] = s;
    __syncthreads();
    if (threadIdx.x == 0) bsum[blockIdx.x] = ws[0] + ws[1] + ws[2] + ws[3];
}

__global__ void scan_boffs(const int* __restrict__ bsum, int* __restrict__ boffs,
                           int* __restrict__ rowptr, int nb, int n) {
    int lane = threadIdx.x;
    int carry = 0;
    for (int base = 0; base < nb; base += 64) {
        int i = base + lane;
        int v = (i < nb) ? bsum[i] : 0;
        int orig = v;
        #pragma unroll
        for (int off = 1; off < 64; off <<= 1) {
            int t = __shfl_up(v, off, 64);
            if (lane >= off) v += t;
        }
        if (i < nb) boffs[i] = carry + v - orig;  // exclusive
        carry += __shfl(v, 63, 64);
    }
    if (lane == 0) rowptr[n] = carry;
}

__global__ __launch_bounds__(256) void scan_write(
    const int* __restrict__ cnt, const int* __restrict__ boffs,
    int* __restrict__ rowptr, int n) {
    int base = blockIdx.x * 1024 + threadIdx.x * 4;
    int4 v = make_int4(0, 0, 0, 0);
    if (base + 3 < n) {
        v = *(const int4*)(cnt + base);
    } else {
        if (base + 0 < n) v.x = cnt[base + 0];
        if (base + 1 < n) v.y = cnt[base + 1];
        if (base + 2 < n) v.z = cnt[base + 2];
        if (base + 3 < n) v.w = cnt[base + 3];
    }
    int t0 = v.x, t1 = t0 + v.y, t2 = t1 + v.z, t3 = t2 + v.w;  // inclusive
    int lane = threadIdx.x & 63, wid = threadIdx.x >> 6;
    int sc = t3;
    #pragma unroll
    for (int off = 1; off < 64; off <<= 1) {
        int t = __shfl_up(sc, off, 64);
        if (lane >= off) sc += t;
    }
    __shared__ int ws[4];
    if (lane == 63) ws[wid] = sc;
    __syncthreads();
    int woff = 0;
    for (int w = 0; w < wid; ++w) woff += ws[w];
    int off0 = boffs[blockIdx.x] + woff + sc - t3;  // exclusive at base
    if (base + 3 < n) {
        *(int4*)(rowptr + base) = make_int4(off0, off0 + t0, off0 + t1, off0 + t2);
    } else {
        if (base + 0 < n) rowptr[base + 0] = off0;
        if (base + 1 < n) rowptr[base + 1] = off0 + t0;
        if (base + 2 < n) rowptr[base + 2] = off0 + t1;
        if (base + 3 < n) rowptr[base + 3] = off0 + t2;
    }
}

// Atomic-free scatter: slot = rowptr[d] + epos[e].
__global__ void scatter_edges(const int* __restrict__ src, const int* __restrict__ dst,
                              const int* __restrict__ epos,
                              const float* __restrict__ dinv, const int* __restrict__ rowptr,
                              unsigned* __restrict__ cwp, int E) {
    int e = blockIdx.x * blockDim.x + threadIdx.x;
    if (e >= E) return;
    int s = __builtin_nontemporal_load(src + e);
    int d = __builtin_nontemporal_load(dst + e);
    int pos = __builtin_nontemporal_load(epos + e);
    int idx = rowptr[d] + pos;
    float w = dinv[s] * dinv[d];
    unsigned pk = (unsigned)(unsigned short)s | ((unsigned)f2h(w) << 16);
    __builtin_nontemporal_store(pk, cwp + idx);
}

// small[] layout (floats):
//   [0:32)a0z [32:64)a1z [64:96)c1z [96:128)a0h [128:160)a1h [160:192)c1h [192:204)probs1
//   [256:2304) M2z   [2304:4352) M2h
//   [4352:4416) q2z [4416:4480) q2h [4480:4544) c2z [4544:4608) c2h [4608:4620) probs2
__global__ __launch_bounds__(256) void prep_kernel(
    const float* __restrict__ W1, const float* __restrict__ b1,
    const float* __restrict__ Wl1, const float* __restrict__ bl1,
    const float* __restrict__ att1,
    const float* __restrict__ W2, const float* __restrict__ b2,
    const float* __restrict__ Wl2, const float* __restrict__ bl2,
    const float* __restrict__ att2, float* __restrict__ small) {
    int tid = threadIdx.x;
    for (int t = tid; t < 192; t += blockDim.x) {
        int which = t >> 5, hh = t & 31;
        int g = (which < 3) ? 0 : 2;
        int kind = which % 3;  // 0:a0 1:a1 2:c
        const float* Wl = Wl1 + g * 64 * 32;
        float s = 0.f;
        if (kind < 2) {
            const float* Wr = W1 + g * 2 * 32 + kind * 32;
            for (int k = 0; k < 32; ++k) s += Wr[k] * Wl[k * 32 + hh];
        } else {
            const float* br = b1 + g * 32;
            for (int k = 0; k < 32; ++k) s += br[k] * Wl[k * 32 + hh];
            s += bl1[g * 32 + hh];
        }
        small[t] = s;
    }
    for (int t = tid; t < 4096; t += blockDim.x) {
        int gg = t >> 11;
        int rem = t & 2047;
        int i = rem >> 6, j = rem & 63;
        int g = gg ? 2 : 0;
        const float* Wl = Wl2 + g * 128 * 64;
        const float* Wr = W2 + g * 33 * 64 + i * 64;
        float s = 0.f;
        for (int k = 0; k < 64; ++k) s += Wr[k] * Wl[k * 64 + j];
        small[256 + gg * 2048 + i * 64 + j] = s;
    }
    for (int t = tid; t < 256; t += blockDim.x) {
        int which = t >> 6, j = t & 63;
        int g = (which == 0 || which == 2) ? 0 : 2;
        const float* Wl = Wl2 + g * 128 * 64;
        float s = 0.f;
        if (which < 2) {
            const float* Wr = W2 + g * 33 * 64 + 32 * 64;
            for (int k = 0; k < 64; ++k) s += Wr[k] * Wl[k * 64 + j];
        } else {
            const float* br = b2 + g * 64;
            for (int k = 0; k < 64; ++k) s += br[k] * Wl[k * 64 + j];
            s += bl2[g * 64 + j];
        }
        small[4352 + which * 64 + j] = s;
    }
    if (tid == 0) {
        float mx = att1[0];
        for (int p = 1; p < 12; ++p) mx = fmaxf(mx, att1[p]);
        float e[12], sm = 0.f;
        for (int p = 0; p < 12; ++p) { e[p] = expf(att1[p] - mx); sm += e[p]; }
        for (int p = 0; p < 12; ++p) small[192 + p] = e[p] / sm;
        mx = att2[0];
        for (int p = 1; p < 12; ++p) mx = fmaxf(mx, att2[p]);
        sm = 0.f;
        for (int p = 0; p < 12; ++p) { e[p] = expf(att2[p] - mx); sm += e[p]; }
        for (int p = 0; p < 12; ++p) small[4608 + p] = e[p] / sm;
    }
}

// One 32-lane group per node. Lanes 0..23 aggregate A_hat x1 (24 ch);
// gathers from padded [N][32] bf16 rows (one 64B line per edge).
__global__ __launch_bounds__(256) void agg1_layer1(
    const float* __restrict__ X, const unsigned short* __restrict__ Xh,
    const int* __restrict__ rowptr, const unsigned* __restrict__ cwp,
    const float* __restrict__ dinv, const float* __restrict__ small,
    unsigned short* __restrict__ hout, unsigned short* __restrict__ atimeh, int n) {
    int lane = threadIdx.x & 31;
    int node = (blockIdx.x * blockDim.x + threadIdx.x) >> 5;
    if (node >= n) return;
    int beg = rowptr[node], end = rowptr[node + 1];
    float acc = 0.f;
    if (lane < 24) {
        float dn = dinv[node];
        acc = dn * dn * __builtin_nontemporal_load(X + (size_t)node * 24 + lane);
        float a0 = 0.f, a1 = 0.f, a2 = 0.f, a3 = 0.f;
        int j = beg;
        for (; j + 4 <= end; j += 4) {
            unsigned c0 = __builtin_nontemporal_load(cwp + j);
            unsigned c1 = __builtin_nontemporal_load(cwp + j + 1);
            unsigned c2 = __builtin_nontemporal_load(cwp + j + 2);
            unsigned c3 = __builtin_nontemporal_load(cwp + j + 3);
            a0 = fmaf(h2f(c0 >> 16), bf2f(Xh[(c0 & 0xFFFFu) * 32 + lane]), a0);
            a1 = fmaf(h2f(c1 >> 16), bf2f(Xh[(c1 & 0xFFFFu) * 32 + lane]), a1);
            a2 = fmaf(h2f(c2 >> 16), bf2f(Xh[(c2 & 0xFFFFu) * 32 + lane]), a2);
            a3 = fmaf(h2f(c3 >> 16), bf2f(Xh[(c3 & 0xFFFFu) * 32 + lane]), a3);
        }
        for (; j < end; ++j) {
            unsigned c = __builtin_nontemporal_load(cwp + j);
            acc = fmaf(h2f(c >> 16), bf2f(Xh[(c & 0xFFFFu) * 32 + lane]), acc);
        }
        acc += (a0 + a1) + (a2 + a3);
    }
    if (lane >= 12 && lane < 24)
        atimeh[(size_t)node * 12 + lane - 12] = f2bf(acc);
    float a0z = small[lane], a1z = small[32 + lane], c1z = small[64 + lane];
    float a0h = small[96 + lane], a1h = small[128 + lane], c1h = small[160 + lane];
    float hs = 0.f;
    #pragma unroll
    for (int p = 0; p < 12; ++p) {
        float x0 = __shfl(acc, p, 32);
        float x1 = __shfl(acc, 12 + p, 32);
        float z = 1.f / (1.f + __expf(-fmaf(x0, a0z, fmaf(x1, a1z, c1z))));
        float ht = tanhf(fmaf(x0, a0h, fmaf(x1, a1h, c1h)));
        hs = fmaf(small[192 + p] * (1.f - z), ht, hs);
    }
    hout[(size_t)node * 32 + lane] = f2bf(fmaxf(hs, 0.f));
}

// Fused agg2 + layer2 + final MLP. One 64-lane wave per node; 8 waves/block.
// Per-wave work-stealing (chunk=2) from 8 partition counters removes the
// static-assignment ramp-down tail. Grid 1024 = one resident generation.
__global__ __launch_bounds__(512, 8) void agg2_layer2(
    const unsigned short* __restrict__ hbuf, const unsigned short* __restrict__ atimeh,
    const int* __restrict__ rowptr, const unsigned* __restrict__ cwp,
    const float* __restrict__ dinv, const float* __restrict__ small,
    const float* __restrict__ lw1, const float* __restrict__ lb1,
    const float* __restrict__ lw2, const float* __restrict__ lb2,
    int* __restrict__ wctr, float* __restrict__ out, int n) {
    __shared__ __align__(16) float4 wqs[1024];          // 16 KB M2z/M2h interleaved
    __shared__ __align__(16) float s_lw1[2048];          // 8 KB [j][k] 64x32
    __shared__ float s_pr[16];
    __shared__ __align__(16) float4 scr[8][16];          // per-wave av/h2 scratch

    for (int t = threadIdx.x; t < 4096; t += 512) {
        int s = t & 3, j = (t >> 2) & 63, k2 = t >> 8;
        int k = 2 * k2 + (s >> 1), zh = s & 1;
        ((float*)wqs)[t] = small[256 + zh * 2048 + k * 64 + j];
    }
    for (int t = threadIdx.x; t < 2048; t += 512) s_lw1[t] = lw1[t];
    if (threadIdx.x < 16) s_pr[threadIdx.x] = (threadIdx.x < 12) ? small[4608 + threadIdx.x] : 0.f;
    __syncthreads();

    int lane = threadIdx.x & 63;
    int wid = threadIdx.x >> 6;
    int ch = lane & 31, half = lane >> 5;
    float qz = small[4352 + lane], qh = small[4416 + lane];
    float czv = small[4480 + lane], chv = small[4544 + lane];
    float lb1v = lb1[ch];
    int p_ = lane & 15, q_ = lane >> 4;
    float lb2v = (q_ == 0 && p_ < 12) ? lb2[p_] : 0.f;
    float wlw2[8];
    #pragma unroll
    for (int i = 0; i < 8; ++i)
        wlw2[i] = (p_ < 12) ? lw2[(q_ * 8 + i) * 12 + p_] : 0.f;

    // work-stealing partition: blocks with same (blockIdx&7) share a counter
    int part = blockIdx.x & 7;
    int pchunk = (n + 7) >> 3;
    int pbeg = part * pchunk;
    int psz = min(pchunk, n - pbeg);

    for (;;) {
        int base = 0;
        if (lane == 0) base = atomicAdd(&wctr[part], 2);
        base = __shfl(base, 0, 64);
        if (base >= psz) break;
        int lastt = min(base + 2, psz);
        for (int t = base; t < lastt; ++t) {
            int node = pbeg + t;
            // early-issue the independent atime row (hides under gather)
            const u2v* trow = (const u2v*)(atimeh + (size_t)node * 12);
            u2v tA = __builtin_nontemporal_load(trow);
            u2v tB = __builtin_nontemporal_load(trow + 1);
            u2v tC = __builtin_nontemporal_load(trow + 2);

            // ---- fused agg2: av[ch] = (A_hat h)[node][ch], bf16 gather ----
            int beg = rowptr[node], end = rowptr[node + 1];
            float dn = dinv[node];
            float acc = (half == 0) ? dn * dn * bf2f(hbuf[(size_t)node * 32 + ch]) : 0.f;
            float a1 = 0.f, a2 = 0.f, a3 = 0.f;
            int j = beg + half;
            for (; j + 6 < end; j += 8) {
                unsigned c0 = __builtin_nontemporal_load(cwp + j);
                unsigned c1 = __builtin_nontemporal_load(cwp + j + 2);
                unsigned c2 = __builtin_nontemporal_load(cwp + j + 4);
                unsigned c3 = __builtin_nontemporal_load(cwp + j + 6);
                acc = fmaf(h2f(c0 >> 16), bf2f(hbuf[(size_t)(c0 & 0xFFFFu) * 32 + ch]), acc);
                a1  = fmaf(h2f(c1 >> 16), bf2f(hbuf[(size_t)(c1 & 0xFFFFu) * 32 + ch]), a1);
                a2  = fmaf(h2f(c2 >> 16), bf2f(hbuf[(size_t)(c2 & 0xFFFFu) * 32 + ch]), a2);
                a3  = fmaf(h2f(c3 >> 16), bf2f(hbuf[(size_t)(c3 & 0xFFFFu) * 32 + ch]), a3);
            }
            for (; j < end; j += 2) {
                unsigned c = __builtin_nontemporal_load(cwp + j);
                acc = fmaf(h2f(c >> 16), bf2f(hbuf[(size_t)(c & 0xFFFFu) * 32 + ch]), acc);
            }
            acc += (a1 + a2) + a3;
            acc += __shfl_xor(acc, 32, 64);   // both halves hold av[ch]

            if (half == 0) ((float*)&scr[wid][0])[ch] = acc;
            asm volatile("s_waitcnt lgkmcnt(0)" ::: "memory");

            // ---- GEMV: p0z/p0h = av . M2z/M2h (col j=lane) ----
            float p0z = czv, p0h = chv;
            const float4* arow = &scr[wid][0];
            #pragma unroll
            for (int c = 0; c < 8; ++c) {
                float4 av = arow[c];
                float4 w0 = wqs[(2 * c) * 64 + lane];
                float4 w1 = wqs[(2 * c + 1) * 64 + lane];
                p0z = fmaf(av.x, w0.x, p0z); p0h = fmaf(av.x, w0.y, p0h);
                p0z = fmaf(av.y, w0.z, p0z); p0h = fmaf(av.y, w0.w, p0h);
                p0z = fmaf(av.z, w1.x, p0z); p0h = fmaf(av.z, w1.y, p0h);
                p0z = fmaf(av.w, w1.z, p0z); p0h = fmaf(av.w, w1.w, p0h);
            }
            float tt[12] = {bf2f((unsigned short)(tA.x & 0xFFFFu)), bf2f((unsigned short)(tA.x >> 16)),
                            bf2f((unsigned short)(tA.y & 0xFFFFu)), bf2f((unsigned short)(tA.y >> 16)),
                            bf2f((unsigned short)(tB.x & 0xFFFFu)), bf2f((unsigned short)(tB.x >> 16)),
                            bf2f((unsigned short)(tB.y & 0xFFFFu)), bf2f((unsigned short)(tB.y >> 16)),
                            bf2f((unsigned short)(tC.x & 0xFFFFu)), bf2f((unsigned short)(tC.x >> 16)),
                            bf2f((unsigned short)(tC.y & 0xFFFFu)), bf2f((unsigned short)(tC.y >> 16))};
            float acc2 = 0.f;
            #pragma unroll
            for (int p = 0; p < 12; ++p) {
                float t2 = tt[p];
                float ez = __expf(-fmaf(t2, qz, p0z));
                float eh = __expf(-2.f * fmaf(t2, qh, p0h));
                float R = __builtin_amdgcn_rcpf((1.f + ez) * (1.f + eh));
                acc2 = fmaf(s_pr[p] * ez * (1.f - eh), R, acc2);
            }
            float h2 = fmaxf(acc2, 0.f);
            ((float*)&scr[wid][0])[lane] = h2;
            asm volatile("s_waitcnt lgkmcnt(0)" ::: "memory");

            // ---- h3 = relu(h2 . lw1 + lb1), split over halves ----
            float h3 = half ? 0.f : lb1v;
            const float4* hrow = &scr[wid][half * 8];
            #pragma unroll
            for (int c = 0; c < 8; ++c) {
                float4 hv = hrow[c];
                int jb = half * 32 + c * 4;
                h3 = fmaf(hv.x, s_lw1[(jb + 0) * 32 + ch], h3);
                h3 = fmaf(hv.y, s_lw1[(jb + 1) * 32 + ch], h3);
                h3 = fmaf(hv.z, s_lw1[(jb + 2) * 32 + ch], h3);
                h3 = fmaf(hv.w, s_lw1[(jb + 3) * 32 + ch], h3);
            }
            h3 += __shfl_xor(h3, 32, 64);
            h3 = fmaxf(h3, 0.f);

            // ---- out = h3 . lw2 + lb2 (lw2 in registers) ----
            float o = lb2v;
            #pragma unroll
            for (int i = 0; i < 8; ++i) {
                float h3k = __shfl(h3, q_ * 8 + i, 64);
                o = fmaf(h3k, wlw2[i], o);
            }
            o += __shfl_xor(o, 16, 64);
            o += __shfl_xor(o, 32, 64);
            if (lane < 12)
                __builtin_nontemporal_store(o, out + (size_t)node * 12 + lane);
        }
    }
}

extern "C" void kernel_launch(void* const* d_in, const int* in_sizes, int n_in,
                              void* d_out, int out_size, void* d_ws, size_t ws_size,
                              hipStream_t stream) {
    const float* x1   = (const float*)d_in[0];
    const int*   eidx = (const int*)d_in[1];
    const float* W1   = (const float*)d_in[4];
    const float* b1   = (const float*)d_in[5];
    const float* Wl1  = (const float*)d_in[6];
    const float* bl1  = (const float*)d_in[7];
    const float* att1 = (const float*)d_in[8];
    const float* W2   = (const float*)d_in[9];
    const float* b2   = (const float*)d_in[10];
    const float* Wl2  = (const float*)d_in[11];
    const float* bl2  = (const float*)d_in[12];
    const float* att2 = (const float*)d_in[13];
    const float* lw1  = (const float*)d_in[14];
    const float* lb1  = (const float*)d_in[15];
    const float* lw2  = (const float*)d_in[16];
    const float* lb2  = (const float*)d_in[17];
    (void)n_in; (void)out_size; (void)ws_size;

    int N = in_sizes[0] / 24;
    int E = in_sizes[1] / 2;
    const int* srcp = eidx;
    const int* dstp = eidx + E;
    int nb = (N + 1023) / 1024;
    int n32 = N * 32;
    int ncb = (n32 / 4 + 255) / 256;        // cvt blocks
    int neb = (E + 255) / 256;              // count blocks

    char* ws = (char*)d_ws;
    size_t off = 0;
    auto alloc = [&](size_t bytes) -> char* {
        char* p = ws + off;
        off += (bytes + 511) & ~(size_t)511;
        return p;
    };
    int*            cnt    = (int*)alloc((size_t)N * 4);
    int*            rowptr = (int*)alloc((size_t)(N + 1) * 4);
    float*          dinv   = (float*)alloc((size_t)N * 4);
    int*            epos   = (int*)alloc((size_t)E * 4);
    unsigned*       cwp    = (unsigned*)alloc((size_t)E * 4);
    unsigned short* x1h    = (unsigned short*)alloc((size_t)n32 * 2);
    unsigned short* hbuf   = (unsigned short*)alloc((size_t)N * 32 * 2);
    unsigned short* atimeh = (unsigned short*)alloc((size_t)N * 12 * 2);
    float*          small  = (float*)alloc(4624 * 4);
    int*            bsum   = (int*)alloc((size_t)nb * 4);
    int*            boffs  = (int*)alloc((size_t)nb * 4);
    int*            wctr   = (int*)alloc(8 * 4);

    (void)hipMemsetAsync(cnt, 0, (size_t)N * 4, stream);
    (void)hipMemsetAsync(wctr, 0, 8 * 4, stream);
    prep_kernel<<<1, 256, 0, stream>>>(W1, b1, Wl1, bl1, att1, W2, b2, Wl2, bl2, att2, small);
    cvt_count<<<ncb + neb, 256, 0, stream>>>(x1, x1h, n32, ncb, dstp, cnt, epos, E);
    scan_blocksum<<<nb, 256, 0, stream>>>(cnt, dinv, bsum, N);
    scan_boffs<<<1, 64, 0, stream>>>(bsum, boffs, rowptr, nb, N);
    scan_write<<<nb, 256, 0, stream>>>(cnt, boffs, rowptr, N);
    scatter_edges<<<neb, 256, 0, stream>>>(srcp, dstp, epos, dinv, rowptr, cwp, E);
    agg1_layer1<<<(N * 32 + 255) / 256, 256, 0, stream>>>(x1, x1h, rowptr, cwp, dinv, small, hbuf, atimeh, N);
    agg2_layer2<<<1024, 512, 0, stream>>>(hbuf, atimeh, rowptr, cwp, dinv, small,
                                          lw1, lb1, lw2, lb2, wctr, (float*)d_out, N);
}

// Round 17
// 187.681 us; speedup vs baseline: 2.8083x; 2.8083x over previous
//
#include <hip/hip_runtime.h>
#include <hip/hip_bf16.h>
#include <hip/hip_fp16.h>
#include <math.h>

// ---------------------------------------------------------------------------
// A3T-GCN two-layer, restructured (see round-1 notes):
//   - H == 0 => R gate dead, cell = (1-Z)*tanh(...)
//   - A_hat commutes with W => one propagation per layer, folded gate matrices
//   - layer2 time channel reuses layer-1 propagation (rank-1 per period)
// Round 17 (resubmit after infra failure): exactly the round-14 kernel —
// static grid-stride agg2, grid 1024. (r15's work-stealing regressed
// catastrophically: 25k same-line device atomics serialized all waves.)
// ---------------------------------------------------------------------------

typedef float f4v __attribute__((ext_vector_type(4)));
typedef unsigned u2v __attribute__((ext_vector_type(2)));

static __device__ __forceinline__ unsigned short f2bf(float f) {
    unsigned u = __float_as_uint(f);
    unsigned r = (u + 0x7FFFu + ((u >> 16) & 1u)) >> 16;  // RNE
    return (unsigned short)r;
}
static __device__ __forceinline__ float bf2f(unsigned short u) {
    return __uint_as_float(((unsigned)u) << 16);
}
static __device__ __forceinline__ unsigned short f2h(float f) {
    __half h = __float2half_rn(f);
    return *reinterpret_cast<unsigned short*>(&h);
}
static __device__ __forceinline__ float h2f(unsigned short u) {
    __half h;
    *reinterpret_cast<unsigned short*>(&h) = u;
    return __half2float(h);
}

// blocks [0, ncb): convert x1 -> padded bf16 rows [N][32] (ch>=24 zero).
// blocks [ncb, ...): count edges, emitting CSR slot epos[e] from the atomic.
__global__ void cvt_count(const float* __restrict__ in, unsigned short* __restrict__ outh,
                          int n32, int ncb,
                          const int* __restrict__ dst, int* __restrict__ cnt,
                          int* __restrict__ epos, int E) {
    if ((int)blockIdx.x < ncb) {
        int i = (blockIdx.x * blockDim.x + threadIdx.x) * 4;
        if (i < n32) {
            int node = i >> 5, c = i & 31;
            const float* row = in + (size_t)node * 24;
            ushort4 u;
            u.x = (c + 0 < 24) ? f2bf(__builtin_nontemporal_load(row + c + 0)) : (unsigned short)0;
            u.y = (c + 1 < 24) ? f2bf(__builtin_nontemporal_load(row + c + 1)) : (unsigned short)0;
            u.z = (c + 2 < 24) ? f2bf(__builtin_nontemporal_load(row + c + 2)) : (unsigned short)0;
            u.w = (c + 3 < 24) ? f2bf(__builtin_nontemporal_load(row + c + 3)) : (unsigned short)0;
            *(ushort4*)(outh + i) = u;
        }
    } else {
        int e = (blockIdx.x - ncb) * blockDim.x + threadIdx.x;
        if (e < E) {
            int d = __builtin_nontemporal_load(dst + e);
            int pos = atomicAdd(&cnt[d], 1);
            __builtin_nontemporal_store(pos, epos + e);
        }
    }
}

// --- parallel exclusive scan of cnt -> rowptr, plus dinv ------------------
__global__ __launch_bounds__(256) void scan_blocksum(
    const int* __restrict__ cnt, float* __restrict__ dinv,
    int* __restrict__ bsum, int n) {
    int base = blockIdx.x * 1024 + threadIdx.x * 4;
    int s = 0;
    if (base + 3 < n) {
        int4 v = *(const int4*)(cnt + base);
        dinv[base + 0] = rsqrtf((float)v.x + 1.f);
        dinv[base + 1] = rsqrtf((float)v.y + 1.f);
        dinv[base + 2] = rsqrtf((float)v.z + 1.f);
        dinv[base + 3] = rsqrtf((float)v.w + 1.f);
        s = v.x + v.y + v.z + v.w;
    } else {
        for (int k = 0; k < 4; ++k)
            if (base + k < n) {
                int v = cnt[base + k];
                dinv[base + k] = rsqrtf((float)v + 1.f);
                s += v;
            }
    }
    #pragma unroll
    for (int off = 32; off > 0; off >>= 1) s += __shfl_down(s, off, 64);
    __shared__ int ws[4];
    int lane = threadIdx.x & 63, wid = threadIdx.x >> 6;
    if (lane == 0) ws[wid] = s;
    __syncthreads();
    if (threadIdx.x == 0) bsum[blockIdx.x] = ws[0] + ws[1] + ws[2] + ws[3];
}

__global__ void scan_boffs(const int* __restrict__ bsum, int* __restrict__ boffs,
                           int* __restrict__ rowptr, int nb, int n) {
    int lane = threadIdx.x;
    int carry = 0;
    for (int base = 0; base < nb; base += 64) {
        int i = base + lane;
        int v = (i < nb) ? bsum[i] : 0;
        int orig = v;
        #pragma unroll
        for (int off = 1; off < 64; off <<= 1) {
            int t = __shfl_up(v, off, 64);
            if (lane >= off) v += t;
        }
        if (i < nb) boffs[i] = carry + v - orig;  // exclusive
        carry += __shfl(v, 63, 64);
    }
    if (lane == 0) rowptr[n] = carry;
}

__global__ __launch_bounds__(256) void scan_write(
    const int* __restrict__ cnt, const int* __restrict__ boffs,
    int* __restrict__ rowptr, int n) {
    int base = blockIdx.x * 1024 + threadIdx.x * 4;
    int4 v = make_int4(0, 0, 0, 0);
    if (base + 3 < n) {
        v = *(const int4*)(cnt + base);
    } else {
        if (base + 0 < n) v.x = cnt[base + 0];
        if (base + 1 < n) v.y = cnt[base + 1];
        if (base + 2 < n) v.z = cnt[base + 2];
        if (base + 3 < n) v.w = cnt[base + 3];
    }
    int t0 = v.x, t1 = t0 + v.y, t2 = t1 + v.z, t3 = t2 + v.w;  // inclusive
    int lane = threadIdx.x & 63, wid = threadIdx.x >> 6;
    int sc = t3;
    #pragma unroll
    for (int off = 1; off < 64; off <<= 1) {
        int t = __shfl_up(sc, off, 64);
        if (lane >= off) sc += t;
    }
    __shared__ int ws[4];
    if (lane == 63) ws[wid] = sc;
    __syncthreads();
    int woff = 0;
    for (int w = 0; w < wid; ++w) woff += ws[w];
    int off0 = boffs[blockIdx.x] + woff + sc - t3;  // exclusive at base
    if (base + 3 < n) {
        *(int4*)(rowptr + base) = make_int4(off0, off0 + t0, off0 + t1, off0 + t2);
    } else {
        if (base + 0 < n) rowptr[base + 0] = off0;
        if (base + 1 < n) rowptr[base + 1] = off0 + t0;
        if (base + 2 < n) rowptr[base + 2] = off0 + t1;
        if (base + 3 < n) rowptr[base + 3] = off0 + t2;
    }
}

// Atomic-free scatter: slot = rowptr[d] + epos[e].
__global__ void scatter_edges(const int* __restrict__ src, const int* __restrict__ dst,
                              const int* __restrict__ epos,
                              const float* __restrict__ dinv, const int* __restrict__ rowptr,
                              unsigned* __restrict__ cwp, int E) {
    int e = blockIdx.x * blockDim.x + threadIdx.x;
    if (e >= E) return;
    int s = __builtin_nontemporal_load(src + e);
    int d = __builtin_nontemporal_load(dst + e);
    int pos = __builtin_nontemporal_load(epos + e);
    int idx = rowptr[d] + pos;
    float w = dinv[s] * dinv[d];
    unsigned pk = (unsigned)(unsigned short)s | ((unsigned)f2h(w) << 16);
    __builtin_nontemporal_store(pk, cwp + idx);
}

// small[] layout (floats):
//   [0:32)a0z [32:64)a1z [64:96)c1z [96:128)a0h [128:160)a1h [160:192)c1h [192:204)probs1
//   [256:2304) M2z   [2304:4352) M2h
//   [4352:4416) q2z [4416:4480) q2h [4480:4544) c2z [4544:4608) c2h [4608:4620) probs2
__global__ __launch_bounds__(256) void prep_kernel(
    const float* __restrict__ W1, const float* __restrict__ b1,
    const float* __restrict__ Wl1, const float* __restrict__ bl1,
    const float* __restrict__ att1,
    const float* __restrict__ W2, const float* __restrict__ b2,
    const float* __restrict__ Wl2, const float* __restrict__ bl2,
    const float* __restrict__ att2, float* __restrict__ small) {
    int tid = threadIdx.x;
    for (int t = tid; t < 192; t += blockDim.x) {
        int which = t >> 5, hh = t & 31;
        int g = (which < 3) ? 0 : 2;
        int kind = which % 3;  // 0:a0 1:a1 2:c
        const float* Wl = Wl1 + g * 64 * 32;
        float s = 0.f;
        if (kind < 2) {
            const float* Wr = W1 + g * 2 * 32 + kind * 32;
            for (int k = 0; k < 32; ++k) s += Wr[k] * Wl[k * 32 + hh];
        } else {
            const float* br = b1 + g * 32;
            for (int k = 0; k < 32; ++k) s += br[k] * Wl[k * 32 + hh];
            s += bl1[g * 32 + hh];
        }
        small[t] = s;
    }
    for (int t = tid; t < 4096; t += blockDim.x) {
        int gg = t >> 11;
        int rem = t & 2047;
        int i = rem >> 6, j = rem & 63;
        int g = gg ? 2 : 0;
        const float* Wl = Wl2 + g * 128 * 64;
        const float* Wr = W2 + g * 33 * 64 + i * 64;
        float s = 0.f;
        for (int k = 0; k < 64; ++k) s += Wr[k] * Wl[k * 64 + j];
        small[256 + gg * 2048 + i * 64 + j] = s;
    }
    for (int t = tid; t < 256; t += blockDim.x) {
        int which = t >> 6, j = t & 63;
        int g = (which == 0 || which == 2) ? 0 : 2;
        const float* Wl = Wl2 + g * 128 * 64;
        float s = 0.f;
        if (which < 2) {
            const float* Wr = W2 + g * 33 * 64 + 32 * 64;
            for (int k = 0; k < 64; ++k) s += Wr[k] * Wl[k * 64 + j];
        } else {
            const float* br = b2 + g * 64;
            for (int k = 0; k < 64; ++k) s += br[k] * Wl[k * 64 + j];
            s += bl2[g * 64 + j];
        }
        small[4352 + which * 64 + j] = s;
    }
    if (tid == 0) {
        float mx = att1[0];
        for (int p = 1; p < 12; ++p) mx = fmaxf(mx, att1[p]);
        float e[12], sm = 0.f;
        for (int p = 0; p < 12; ++p) { e[p] = expf(att1[p] - mx); sm += e[p]; }
        for (int p = 0; p < 12; ++p) small[192 + p] = e[p] / sm;
        mx = att2[0];
        for (int p = 1; p < 12; ++p) mx = fmaxf(mx, att2[p]);
        sm = 0.f;
        for (int p = 0; p < 12; ++p) { e[p] = expf(att2[p] - mx); sm += e[p]; }
        for (int p = 0; p < 12; ++p) small[4608 + p] = e[p] / sm;
    }
}

// One 32-lane group per node. Lanes 0..23 aggregate A_hat x1 (24 ch);
// gathers from padded [N][32] bf16 rows (one 64B line per edge).
__global__ __launch_bounds__(256) void agg1_layer1(
    const float* __restrict__ X, const unsigned short* __restrict__ Xh,
    const int* __restrict__ rowptr, const unsigned* __restrict__ cwp,
    const float* __restrict__ dinv, const float* __restrict__ small,
    unsigned short* __restrict__ hout, unsigned short* __restrict__ atimeh, int n) {
    int lane = threadIdx.x & 31;
    int node = (blockIdx.x * blockDim.x + threadIdx.x) >> 5;
    if (node >= n) return;
    int beg = rowptr[node], end = rowptr[node + 1];
    float acc = 0.f;
    if (lane < 24) {
        float dn = dinv[node];
        acc = dn * dn * __builtin_nontemporal_load(X + (size_t)node * 24 + lane);
        float a0 = 0.f, a1 = 0.f, a2 = 0.f, a3 = 0.f;
        int j = beg;
        for (; j + 4 <= end; j += 4) {
            unsigned c0 = __builtin_nontemporal_load(cwp + j);
            unsigned c1 = __builtin_nontemporal_load(cwp + j + 1);
            unsigned c2 = __builtin_nontemporal_load(cwp + j + 2);
            unsigned c3 = __builtin_nontemporal_load(cwp + j + 3);
            a0 = fmaf(h2f(c0 >> 16), bf2f(Xh[(c0 & 0xFFFFu) * 32 + lane]), a0);
            a1 = fmaf(h2f(c1 >> 16), bf2f(Xh[(c1 & 0xFFFFu) * 32 + lane]), a1);
            a2 = fmaf(h2f(c2 >> 16), bf2f(Xh[(c2 & 0xFFFFu) * 32 + lane]), a2);
            a3 = fmaf(h2f(c3 >> 16), bf2f(Xh[(c3 & 0xFFFFu) * 32 + lane]), a3);
        }
        for (; j < end; ++j) {
            unsigned c = __builtin_nontemporal_load(cwp + j);
            acc = fmaf(h2f(c >> 16), bf2f(Xh[(c & 0xFFFFu) * 32 + lane]), acc);
        }
        acc += (a0 + a1) + (a2 + a3);
    }
    if (lane >= 12 && lane < 24)
        atimeh[(size_t)node * 12 + lane - 12] = f2bf(acc);
    float a0z = small[lane], a1z = small[32 + lane], c1z = small[64 + lane];
    float a0h = small[96 + lane], a1h = small[128 + lane], c1h = small[160 + lane];
    float hs = 0.f;
    #pragma unroll
    for (int p = 0; p < 12; ++p) {
        float x0 = __shfl(acc, p, 32);
        float x1 = __shfl(acc, 12 + p, 32);
        float z = 1.f / (1.f + __expf(-fmaf(x0, a0z, fmaf(x1, a1z, c1z))));
        float ht = tanhf(fmaf(x0, a0h, fmaf(x1, a1h, c1h)));
        hs = fmaf(small[192 + p] * (1.f - z), ht, hs);
    }
    hout[(size_t)node * 32 + lane] = f2bf(fmaxf(hs, 0.f));
}

// Fused agg2 + layer2 + final MLP. One 64-lane wave per node; 8 waves/block
// share the LDS weight tiles -> 4 blocks/CU = 32 waves/CU. Grid 1024 = one
// resident generation, static grid-stride.
__global__ __launch_bounds__(512, 8) void agg2_layer2(
    const unsigned short* __restrict__ hbuf, const unsigned short* __restrict__ atimeh,
    const int* __restrict__ rowptr, const unsigned* __restrict__ cwp,
    const float* __restrict__ dinv, const float* __restrict__ small,
    const float* __restrict__ lw1, const float* __restrict__ lb1,
    const float* __restrict__ lw2, const float* __restrict__ lb2,
    float* __restrict__ out, int n) {
    __shared__ __align__(16) float4 wqs[1024];          // 16 KB M2z/M2h interleaved
    __shared__ __align__(16) float s_lw1[2048];          // 8 KB [j][k] 64x32
    __shared__ float s_pr[16];
    __shared__ __align__(16) float4 scr[8][16];          // per-wave av/h2 scratch

    for (int t = threadIdx.x; t < 4096; t += 512) {
        int s = t & 3, j = (t >> 2) & 63, k2 = t >> 8;
        int k = 2 * k2 + (s >> 1), zh = s & 1;
        ((float*)wqs)[t] = small[256 + zh * 2048 + k * 64 + j];
    }
    for (int t = threadIdx.x; t < 2048; t += 512) s_lw1[t] = lw1[t];
    if (threadIdx.x < 16) s_pr[threadIdx.x] = (threadIdx.x < 12) ? small[4608 + threadIdx.x] : 0.f;
    __syncthreads();

    int lane = threadIdx.x & 63;
    int wid = threadIdx.x >> 6;
    int ch = lane & 31, half = lane >> 5;
    float qz = small[4352 + lane], qh = small[4416 + lane];
    float czv = small[4480 + lane], chv = small[4544 + lane];
    float lb1v = lb1[ch];
    int p_ = lane & 15, q_ = lane >> 4;
    float lb2v = (q_ == 0 && p_ < 12) ? lb2[p_] : 0.f;
    float wlw2[8];
    #pragma unroll
    for (int i = 0; i < 8; ++i)
        wlw2[i] = (p_ < 12) ? lw2[(q_ * 8 + i) * 12 + p_] : 0.f;

    int totalw = gridDim.x * 8;
    for (int node = blockIdx.x * 8 + wid; node < n; node += totalw) {
        // early-issue the independent atime row (hides under gather)
        const u2v* trow = (const u2v*)(atimeh + (size_t)node * 12);
        u2v tA = __builtin_nontemporal_load(trow);
        u2v tB = __builtin_nontemporal_load(trow + 1);
        u2v tC = __builtin_nontemporal_load(trow + 2);

        // ---- fused agg2: av[ch] = (A_hat h)[node][ch], bf16 gather ----
        int beg = rowptr[node], end = rowptr[node + 1];
        float dn = dinv[node];
        float acc = (half == 0) ? dn * dn * bf2f(hbuf[(size_t)node * 32 + ch]) : 0.f;
        float a1 = 0.f, a2 = 0.f, a3 = 0.f;
        int j = beg + half;
        for (; j + 6 < end; j += 8) {
            unsigned c0 = __builtin_nontemporal_load(cwp + j);
            unsigned c1 = __builtin_nontemporal_load(cwp + j + 2);
            unsigned c2 = __builtin_nontemporal_load(cwp + j + 4);
            unsigned c3 = __builtin_nontemporal_load(cwp + j + 6);
            acc = fmaf(h2f(c0 >> 16), bf2f(hbuf[(size_t)(c0 & 0xFFFFu) * 32 + ch]), acc);
            a1  = fmaf(h2f(c1 >> 16), bf2f(hbuf[(size_t)(c1 & 0xFFFFu) * 32 + ch]), a1);
            a2  = fmaf(h2f(c2 >> 16), bf2f(hbuf[(size_t)(c2 & 0xFFFFu) * 32 + ch]), a2);
            a3  = fmaf(h2f(c3 >> 16), bf2f(hbuf[(size_t)(c3 & 0xFFFFu) * 32 + ch]), a3);
        }
        for (; j < end; j += 2) {
            unsigned c = __builtin_nontemporal_load(cwp + j);
            acc = fmaf(h2f(c >> 16), bf2f(hbuf[(size_t)(c & 0xFFFFu) * 32 + ch]), acc);
        }
        acc += (a1 + a2) + a3;
        acc += __shfl_xor(acc, 32, 64);   // both halves hold av[ch]

        if (half == 0) ((float*)&scr[wid][0])[ch] = acc;
        asm volatile("s_waitcnt lgkmcnt(0)" ::: "memory");

        // ---- GEMV: p0z/p0h = av . M2z/M2h (col j=lane) ----
        float p0z = czv, p0h = chv;
        const float4* arow = &scr[wid][0];
        #pragma unroll
        for (int c = 0; c < 8; ++c) {
            float4 av = arow[c];
            float4 w0 = wqs[(2 * c) * 64 + lane];
            float4 w1 = wqs[(2 * c + 1) * 64 + lane];
            p0z = fmaf(av.x, w0.x, p0z); p0h = fmaf(av.x, w0.y, p0h);
            p0z = fmaf(av.y, w0.z, p0z); p0h = fmaf(av.y, w0.w, p0h);
            p0z = fmaf(av.z, w1.x, p0z); p0h = fmaf(av.z, w1.y, p0h);
            p0z = fmaf(av.w, w1.z, p0z); p0h = fmaf(av.w, w1.w, p0h);
        }
        float tt[12] = {bf2f((unsigned short)(tA.x & 0xFFFFu)), bf2f((unsigned short)(tA.x >> 16)),
                        bf2f((unsigned short)(tA.y & 0xFFFFu)), bf2f((unsigned short)(tA.y >> 16)),
                        bf2f((unsigned short)(tB.x & 0xFFFFu)), bf2f((unsigned short)(tB.x >> 16)),
                        bf2f((unsigned short)(tB.y & 0xFFFFu)), bf2f((unsigned short)(tB.y >> 16)),
                        bf2f((unsigned short)(tC.x & 0xFFFFu)), bf2f((unsigned short)(tC.x >> 16)),
                        bf2f((unsigned short)(tC.y & 0xFFFFu)), bf2f((unsigned short)(tC.y >> 16))};
        float acc2 = 0.f;
        #pragma unroll
        for (int p = 0; p < 12; ++p) {
            float t = tt[p];
            float ez = __expf(-fmaf(t, qz, p0z));
            float eh = __expf(-2.f * fmaf(t, qh, p0h));
            float R = __builtin_amdgcn_rcpf((1.f + ez) * (1.f + eh));
            acc2 = fmaf(s_pr[p] * ez * (1.f - eh), R, acc2);
        }
        float h2 = fmaxf(acc2, 0.f);
        ((float*)&scr[wid][0])[lane] = h2;
        asm volatile("s_waitcnt lgkmcnt(0)" ::: "memory");

        // ---- h3 = relu(h2 . lw1 + lb1), split over halves ----
        float h3 = half ? 0.f : lb1v;
        const float4* hrow = &scr[wid][half * 8];
        #pragma unroll
        for (int c = 0; c < 8; ++c) {
            float4 hv = hrow[c];
            int jb = half * 32 + c * 4;
            h3 = fmaf(hv.x, s_lw1[(jb + 0) * 32 + ch], h3);
            h3 = fmaf(hv.y, s_lw1[(jb + 1) * 32 + ch], h3);
            h3 = fmaf(hv.z, s_lw1[(jb + 2) * 32 + ch], h3);
            h3 = fmaf(hv.w, s_lw1[(jb + 3) * 32 + ch], h3);
        }
        h3 += __shfl_xor(h3, 32, 64);
        h3 = fmaxf(h3, 0.f);

        // ---- out = h3 . lw2 + lb2 (lw2 in registers) ----
        float o = lb2v;
        #pragma unroll
        for (int i = 0; i < 8; ++i) {
            float h3k = __shfl(h3, q_ * 8 + i, 64);
            o = fmaf(h3k, wlw2[i], o);
        }
        o += __shfl_xor(o, 16, 64);
        o += __shfl_xor(o, 32, 64);
        if (lane < 12)
            __builtin_nontemporal_store(o, out + (size_t)node * 12 + lane);
    }
}

extern "C" void kernel_launch(void* const* d_in, const int* in_sizes, int n_in,
                              void* d_out, int out_size, void* d_ws, size_t ws_size,
                              hipStream_t stream) {
    const float* x1   = (const float*)d_in[0];
    const int*   eidx = (const int*)d_in[1];
    const float* W1   = (const float*)d_in[4];
    const float* b1   = (const float*)d_in[5];
    const float* Wl1  = (const float*)d_in[6];
    const float* bl1  = (const float*)d_in[7];
    const float* att1 = (const float*)d_in[8];
    const float* W2   = (const float*)d_in[9];
    const float* b2   = (const float*)d_in[10];
    const float* Wl2  = (const float*)d_in[11];
    const float* bl2  = (const float*)d_in[12];
    const float* att2 = (const float*)d_in[13];
    const float* lw1  = (const float*)d_in[14];
    const float* lb1  = (const float*)d_in[15];
    const float* lw2  = (const float*)d_in[16];
    const float* lb2  = (const float*)d_in[17];
    (void)n_in; (void)out_size; (void)ws_size;

    int N = in_sizes[0] / 24;
    int E = in_sizes[1] / 2;
    const int* srcp = eidx;
    const int* dstp = eidx + E;
    int nb = (N + 1023) / 1024;
    int n32 = N * 32;
    int ncb = (n32 / 4 + 255) / 256;        // cvt blocks
    int neb = (E + 255) / 256;              // count blocks

    char* ws = (char*)d_ws;
    size_t off = 0;
    auto alloc = [&](size_t bytes) -> char* {
        char* p = ws + off;
        off += (bytes + 511) & ~(size_t)511;
        return p;
    };
    int*            cnt    = (int*)alloc((size_t)N * 4);
    int*            rowptr = (int*)alloc((size_t)(N + 1) * 4);
    float*          dinv   = (float*)alloc((size_t)N * 4);
    int*            epos   = (int*)alloc((size_t)E * 4);
    unsigned*       cwp    = (unsigned*)alloc((size_t)E * 4);
    unsigned short* x1h    = (unsigned short*)alloc((size_t)n32 * 2);
    unsigned short* hbuf   = (unsigned short*)alloc((size_t)N * 32 * 2);
    unsigned short* atimeh = (unsigned short*)alloc((size_t)N * 12 * 2);
    float*          small  = (float*)alloc(4624 * 4);
    int*            bsum   = (int*)alloc((size_t)nb * 4);
    int*            boffs  = (int*)alloc((size_t)nb * 4);

    (void)hipMemsetAsync(cnt, 0, (size_t)N * 4, stream);
    prep_kernel<<<1, 256, 0, stream>>>(W1, b1, Wl1, bl1, att1, W2, b2, Wl2, bl2, att2, small);
    cvt_count<<<ncb + neb, 256, 0, stream>>>(x1, x1h, n32, ncb, dstp, cnt, epos, E);
    scan_blocksum<<<nb, 256, 0, stream>>>(cnt, dinv, bsum, N);
    scan_boffs<<<1, 64, 0, stream>>>(bsum, boffs, rowptr, nb, N);
    scan_write<<<nb, 256, 0, stream>>>(cnt, boffs, rowptr, N);
    scatter_edges<<<neb, 256, 0, stream>>>(srcp, dstp, epos, dinv, rowptr, cwp, E);
    agg1_layer1<<<(N * 32 + 255) / 256, 256, 0, stream>>>(x1, x1h, rowptr, cwp, dinv, small, hbuf, atimeh, N);
    agg2_layer2<<<1024, 512, 0, stream>>>(hbuf, atimeh, rowptr, cwp, dinv, small,
                                          lw1, lb1, lw2, lb2, (float*)d_out, N);
}

// Round 19
// 156.451 us; speedup vs baseline: 3.3688x; 1.1996x over previous
//
#include <hip/hip_runtime.h>
#include <hip/hip_bf16.h>
#include <hip/hip_fp16.h>
#include <math.h>

// ---------------------------------------------------------------------------
// A3T-GCN two-layer, restructured (see round-1 notes):
//   - H == 0 => R gate dead, cell = (1-Z)*tanh(...)
//   - A_hat commutes with W => one propagation per layer, folded gate matrices
//   - layer2 time channel reuses layer-1 propagation (rank-1 per period)
// Round 19 (resubmit after infra failure): (a) agg1 gates switched from libm
// tanhf + exact-div to the one-rcp fused form validated in agg2; (b)
// prep_kernel merged into cvt_count as a leading 17-block range so its
// serial head-of-chain latency hides under the cvt/count phase.
// ---------------------------------------------------------------------------

typedef float f4v __attribute__((ext_vector_type(4)));
typedef unsigned u2v __attribute__((ext_vector_type(2)));

#define PREPB 17  // prep block range at the head of prep_cvt_count

static __device__ __forceinline__ unsigned short f2bf(float f) {
    unsigned u = __float_as_uint(f);
    unsigned r = (u + 0x7FFFu + ((u >> 16) & 1u)) >> 16;  // RNE
    return (unsigned short)r;
}
static __device__ __forceinline__ float bf2f(unsigned short u) {
    return __uint_as_float(((unsigned)u) << 16);
}
static __device__ __forceinline__ unsigned short f2h(float f) {
    __half h = __float2half_rn(f);
    return *reinterpret_cast<unsigned short*>(&h);
}
static __device__ __forceinline__ float h2f(unsigned short u) {
    __half h;
    *reinterpret_cast<unsigned short*>(&h) = u;
    return __half2float(h);
}

// small[] layout (floats):
//   [0:32)a0z [32:64)a1z [64:96)c1z [96:128)a0h [128:160)a1h [160:192)c1h [192:204)probs1
//   [256:2304) M2z   [2304:4352) M2h
//   [4352:4416) q2z [4416:4480) q2h [4480:4544) c2z [4544:4608) c2h [4608:4620) probs2
// blocks [0,PREPB): weight folding (block 0: layer-1 folds + q/c + softmax;
//   blocks 1..16: M2 fold, one 64-dot per thread).
// blocks [PREPB, PREPB+ncb): convert x1 -> padded bf16 rows [N][32].
// blocks [PREPB+ncb, ...): count edges, emitting CSR slot epos[e].
__global__ void prep_cvt_count(
    const float* __restrict__ in, unsigned short* __restrict__ outh,
    int n32, int ncb,
    const int* __restrict__ dst, int* __restrict__ cnt,
    int* __restrict__ epos, int E,
    const float* __restrict__ W1, const float* __restrict__ b1,
    const float* __restrict__ Wl1, const float* __restrict__ bl1,
    const float* __restrict__ att1,
    const float* __restrict__ W2, const float* __restrict__ b2,
    const float* __restrict__ Wl2, const float* __restrict__ bl2,
    const float* __restrict__ att2, float* __restrict__ small) {
    int tid = threadIdx.x;
    if ((int)blockIdx.x < PREPB) {
        if (blockIdx.x == 0) {
            if (tid < 192) {  // layer-1 folds
                int which = tid >> 5, hh = tid & 31;
                int g = (which < 3) ? 0 : 2;
                int kind = which % 3;  // 0:a0 1:a1 2:c
                const float* Wl = Wl1 + g * 64 * 32;
                float s = 0.f;
                if (kind < 2) {
                    const float* Wr = W1 + g * 2 * 32 + kind * 32;
                    for (int k = 0; k < 32; ++k) s += Wr[k] * Wl[k * 32 + hh];
                } else {
                    const float* br = b1 + g * 32;
                    for (int k = 0; k < 32; ++k) s += br[k] * Wl[k * 32 + hh];
                    s += bl1[g * 32 + hh];
                }
                small[tid] = s;
            }
            {  // q (time row) and c (bias) folds: 256 outputs
                int which = tid >> 6, j = tid & 63;
                int g = (which == 0 || which == 2) ? 0 : 2;
                const float* Wl = Wl2 + g * 128 * 64;
                float s = 0.f;
                if (which < 2) {
                    const float* Wr = W2 + g * 33 * 64 + 32 * 64;
                    for (int k = 0; k < 64; ++k) s += Wr[k] * Wl[k * 64 + j];
                } else {
                    const float* br = b2 + g * 64;
                    for (int k = 0; k < 64; ++k) s += br[k] * Wl[k * 64 + j];
                    s += bl2[g * 64 + j];
                }
                small[4352 + tid] = s;
            }
            if (tid == 0) {  // softmax(att1)
                float mx = att1[0];
                for (int p = 1; p < 12; ++p) mx = fmaxf(mx, att1[p]);
                float e[12], sm = 0.f;
                for (int p = 0; p < 12; ++p) { e[p] = expf(att1[p] - mx); sm += e[p]; }
                for (int p = 0; p < 12; ++p) small[192 + p] = e[p] / sm;
            } else if (tid == 1) {  // softmax(att2)
                float mx = att2[0];
                for (int p = 1; p < 12; ++p) mx = fmaxf(mx, att2[p]);
                float e[12], sm = 0.f;
                for (int p = 0; p < 12; ++p) { e[p] = expf(att2[p] - mx); sm += e[p]; }
                for (int p = 0; p < 12; ++p) small[4608 + p] = e[p] / sm;
            }
        } else {  // blocks 1..16: M2 fold, t in [0,4096)
            int t = (blockIdx.x - 1) * 256 + tid;
            int gg = t >> 11;
            int rem = t & 2047;
            int i = rem >> 6, j = rem & 63;
            int g = gg ? 2 : 0;
            const float* Wl = Wl2 + g * 128 * 64;
            const float* Wr = W2 + g * 33 * 64 + i * 64;
            float s = 0.f;
            for (int k = 0; k < 64; ++k) s += Wr[k] * Wl[k * 64 + j];
            small[256 + gg * 2048 + i * 64 + j] = s;
        }
    } else if ((int)blockIdx.x < PREPB + ncb) {
        int i = ((blockIdx.x - PREPB) * blockDim.x + tid) * 4;
        if (i < n32) {
            int node = i >> 5, c = i & 31;
            const float* row = in + (size_t)node * 24;
            ushort4 u;
            u.x = (c + 0 < 24) ? f2bf(__builtin_nontemporal_load(row + c + 0)) : (unsigned short)0;
            u.y = (c + 1 < 24) ? f2bf(__builtin_nontemporal_load(row + c + 1)) : (unsigned short)0;
            u.z = (c + 2 < 24) ? f2bf(__builtin_nontemporal_load(row + c + 2)) : (unsigned short)0;
            u.w = (c + 3 < 24) ? f2bf(__builtin_nontemporal_load(row + c + 3)) : (unsigned short)0;
            *(ushort4*)(outh + i) = u;
        }
    } else {
        int e = ((int)blockIdx.x - PREPB - ncb) * blockDim.x + tid;
        if (e < E) {
            int d = __builtin_nontemporal_load(dst + e);
            int pos = atomicAdd(&cnt[d], 1);
            __builtin_nontemporal_store(pos, epos + e);
        }
    }
}

// --- parallel exclusive scan of cnt -> rowptr, plus dinv ------------------
__global__ __launch_bounds__(256) void scan_blocksum(
    const int* __restrict__ cnt, float* __restrict__ dinv,
    int* __restrict__ bsum, int n) {
    int base = blockIdx.x * 1024 + threadIdx.x * 4;
    int s = 0;
    if (base + 3 < n) {
        int4 v = *(const int4*)(cnt + base);
        dinv[base + 0] = rsqrtf((float)v.x + 1.f);
        dinv[base + 1] = rsqrtf((float)v.y + 1.f);
        dinv[base + 2] = rsqrtf((float)v.z + 1.f);
        dinv[base + 3] = rsqrtf((float)v.w + 1.f);
        s = v.x + v.y + v.z + v.w;
    } else {
        for (int k = 0; k < 4; ++k)
            if (base + k < n) {
                int v = cnt[base + k];
                dinv[base + k] = rsqrtf((float)v + 1.f);
                s += v;
            }
    }
    #pragma unroll
    for (int off = 32; off > 0; off >>= 1) s += __shfl_down(s, off, 64);
    __shared__ int ws[4];
    int lane = threadIdx.x & 63, wid = threadIdx.x >> 6;
    if (lane == 0) ws[wid] = s;
    __syncthreads();
    if (threadIdx.x == 0) bsum[blockIdx.x] = ws[0] + ws[1] + ws[2] + ws[3];
}

__global__ void scan_boffs(const int* __restrict__ bsum, int* __restrict__ boffs,
                           int* __restrict__ rowptr, int nb, int n) {
    int lane = threadIdx.x;
    int carry = 0;
    for (int base = 0; base < nb; base += 64) {
        int i = base + lane;
        int v = (i < nb) ? bsum[i] : 0;
        int orig = v;
        #pragma unroll
        for (int off = 1; off < 64; off <<= 1) {
            int t = __shfl_up(v, off, 64);
            if (lane >= off) v += t;
        }
        if (i < nb) boffs[i] = carry + v - orig;  // exclusive
        carry += __shfl(v, 63, 64);
    }
    if (lane == 0) rowptr[n] = carry;
}

__global__ __launch_bounds__(256) void scan_write(
    const int* __restrict__ cnt, const int* __restrict__ boffs,
    int* __restrict__ rowptr, int n) {
    int base = blockIdx.x * 1024 + threadIdx.x * 4;
    int4 v = make_int4(0, 0, 0, 0);
    if (base + 3 < n) {
        v = *(const int4*)(cnt + base);
    } else {
        if (base + 0 < n) v.x = cnt[base + 0];
        if (base + 1 < n) v.y = cnt[base + 1];
        if (base + 2 < n) v.z = cnt[base + 2];
        if (base + 3 < n) v.w = cnt[base + 3];
    }
    int t0 = v.x, t1 = t0 + v.y, t2 = t1 + v.z, t3 = t2 + v.w;  // inclusive
    int lane = threadIdx.x & 63, wid = threadIdx.x >> 6;
    int sc = t3;
    #pragma unroll
    for (int off = 1; off < 64; off <<= 1) {
        int t = __shfl_up(sc, off, 64);
        if (lane >= off) sc += t;
    }
    __shared__ int ws[4];
    if (lane == 63) ws[wid] = sc;
    __syncthreads();
    int woff = 0;
    for (int w = 0; w < wid; ++w) woff += ws[w];
    int off0 = boffs[blockIdx.x] + woff + sc - t3;  // exclusive at base
    if (base + 3 < n) {
        *(int4*)(rowptr + base) = make_int4(off0, off0 + t0, off0 + t1, off0 + t2);
    } else {
        if (base + 0 < n) rowptr[base + 0] = off0;
        if (base + 1 < n) rowptr[base + 1] = off0 + t0;
        if (base + 2 < n) rowptr[base + 2] = off0 + t1;
        if (base + 3 < n) rowptr[base + 3] = off0 + t2;
    }
}

// Atomic-free scatter: slot = rowptr[d] + epos[e].
__global__ void scatter_edges(const int* __restrict__ src, const int* __restrict__ dst,
                              const int* __restrict__ epos,
                              const float* __restrict__ dinv, const int* __restrict__ rowptr,
                              unsigned* __restrict__ cwp, int E) {
    int e = blockIdx.x * blockDim.x + threadIdx.x;
    if (e >= E) return;
    int s = __builtin_nontemporal_load(src + e);
    int d = __builtin_nontemporal_load(dst + e);
    int pos = __builtin_nontemporal_load(epos + e);
    int idx = rowptr[d] + pos;
    float w = dinv[s] * dinv[d];
    unsigned pk = (unsigned)(unsigned short)s | ((unsigned)f2h(w) << 16);
    __builtin_nontemporal_store(pk, cwp + idx);
}

// One 32-lane group per node. Lanes 0..23 aggregate A_hat x1 (24 ch);
// gathers from padded [N][32] bf16 rows (one 64B line per edge).
// Gates use the one-rcp fused form (validated in agg2): no tanhf/div.
__global__ __launch_bounds__(256) void agg1_layer1(
    const float* __restrict__ X, const unsigned short* __restrict__ Xh,
    const int* __restrict__ rowptr, const unsigned* __restrict__ cwp,
    const float* __restrict__ dinv, const float* __restrict__ small,
    unsigned short* __restrict__ hout, unsigned short* __restrict__ atimeh, int n) {
    int lane = threadIdx.x & 31;
    int node = (blockIdx.x * blockDim.x + threadIdx.x) >> 5;
    if (node >= n) return;
    int beg = rowptr[node], end = rowptr[node + 1];
    float acc = 0.f;
    if (lane < 24) {
        float dn = dinv[node];
        acc = dn * dn * __builtin_nontemporal_load(X + (size_t)node * 24 + lane);
        float a0 = 0.f, a1 = 0.f, a2 = 0.f, a3 = 0.f;
        int j = beg;
        for (; j + 4 <= end; j += 4) {
            unsigned c0 = __builtin_nontemporal_load(cwp + j);
            unsigned c1 = __builtin_nontemporal_load(cwp + j + 1);
            unsigned c2 = __builtin_nontemporal_load(cwp + j + 2);
            unsigned c3 = __builtin_nontemporal_load(cwp + j + 3);
            a0 = fmaf(h2f(c0 >> 16), bf2f(Xh[(c0 & 0xFFFFu) * 32 + lane]), a0);
            a1 = fmaf(h2f(c1 >> 16), bf2f(Xh[(c1 & 0xFFFFu) * 32 + lane]), a1);
            a2 = fmaf(h2f(c2 >> 16), bf2f(Xh[(c2 & 0xFFFFu) * 32 + lane]), a2);
            a3 = fmaf(h2f(c3 >> 16), bf2f(Xh[(c3 & 0xFFFFu) * 32 + lane]), a3);
        }
        for (; j < end; ++j) {
            unsigned c = __builtin_nontemporal_load(cwp + j);
            acc = fmaf(h2f(c >> 16), bf2f(Xh[(c & 0xFFFFu) * 32 + lane]), acc);
        }
        acc += (a0 + a1) + (a2 + a3);
    }
    if (lane >= 12 && lane < 24)
        atimeh[(size_t)node * 12 + lane - 12] = f2bf(acc);
    float a0z = small[lane], a1z = small[32 + lane], c1z = small[64 + lane];
    float a0h = small[96 + lane], a1h = small[128 + lane], c1h = small[160 + lane];
    float hs = 0.f;
    #pragma unroll
    for (int p = 0; p < 12; ++p) {
        float x0 = __shfl(acc, p, 32);
        float x1 = __shfl(acc, 12 + p, 32);
        float ez = __expf(-fmaf(x0, a0z, fmaf(x1, a1z, c1z)));
        float eh = __expf(-2.f * fmaf(x0, a0h, fmaf(x1, a1h, c1h)));
        // (1-sig(z))*tanh(h) = ez*(1-eh) / ((1+ez)*(1+eh))  -- one rcp
        float R = __builtin_amdgcn_rcpf((1.f + ez) * (1.f + eh));
        hs = fmaf(small[192 + p] * ez * (1.f - eh), R, hs);
    }
    hout[(size_t)node * 32 + lane] = f2bf(fmaxf(hs, 0.f));
}

// Fused agg2 + layer2 + final MLP. One 64-lane wave per node; 8 waves/block
// share the LDS weight tiles -> 4 blocks/CU = 32 waves/CU. Grid 1024 = one
// resident generation, static grid-stride.
__global__ __launch_bounds__(512, 8) void agg2_layer2(
    const unsigned short* __restrict__ hbuf, const unsigned short* __restrict__ atimeh,
    const int* __restrict__ rowptr, const unsigned* __restrict__ cwp,
    const float* __restrict__ dinv, const float* __restrict__ small,
    const float* __restrict__ lw1, const float* __restrict__ lb1,
    const float* __restrict__ lw2, const float* __restrict__ lb2,
    float* __restrict__ out, int n) {
    __shared__ __align__(16) float4 wqs[1024];          // 16 KB M2z/M2h interleaved
    __shared__ __align__(16) float s_lw1[2048];          // 8 KB [j][k] 64x32
    __shared__ float s_pr[16];
    __shared__ __align__(16) float4 scr[8][16];          // per-wave av/h2 scratch

    for (int t = threadIdx.x; t < 4096; t += 512) {
        int s = t & 3, j = (t >> 2) & 63, k2 = t >> 8;
        int k = 2 * k2 + (s >> 1), zh = s & 1;
        ((float*)wqs)[t] = small[256 + zh * 2048 + k * 64 + j];
    }
    for (int t = threadIdx.x; t < 2048; t += 512) s_lw1[t] = lw1[t];
    if (threadIdx.x < 16) s_pr[threadIdx.x] = (threadIdx.x < 12) ? small[4608 + threadIdx.x] : 0.f;
    __syncthreads();

    int lane = threadIdx.x & 63;
    int wid = threadIdx.x >> 6;
    int ch = lane & 31, half = lane >> 5;
    float qz = small[4352 + lane], qh = small[4416 + lane];
    float czv = small[4480 + lane], chv = small[4544 + lane];
    float lb1v = lb1[ch];
    int p_ = lane & 15, q_ = lane >> 4;
    float lb2v = (q_ == 0 && p_ < 12) ? lb2[p_] : 0.f;
    float wlw2[8];
    #pragma unroll
    for (int i = 0; i < 8; ++i)
        wlw2[i] = (p_ < 12) ? lw2[(q_ * 8 + i) * 12 + p_] : 0.f;

    int totalw = gridDim.x * 8;
    for (int node = blockIdx.x * 8 + wid; node < n; node += totalw) {
        // early-issue the independent atime row (hides under gather)
        const u2v* trow = (const u2v*)(atimeh + (size_t)node * 12);
        u2v tA = __builtin_nontemporal_load(trow);
        u2v tB = __builtin_nontemporal_load(trow + 1);
        u2v tC = __builtin_nontemporal_load(trow + 2);

        // ---- fused agg2: av[ch] = (A_hat h)[node][ch], bf16 gather ----
        int beg = rowptr[node], end = rowptr[node + 1];
        float dn = dinv[node];
        float acc = (half == 0) ? dn * dn * bf2f(hbuf[(size_t)node * 32 + ch]) : 0.f;
        float a1 = 0.f, a2 = 0.f, a3 = 0.f;
        int j = beg + half;
        for (; j + 6 < end; j += 8) {
            unsigned c0 = __builtin_nontemporal_load(cwp + j);
            unsigned c1 = __builtin_nontemporal_load(cwp + j + 2);
            unsigned c2 = __builtin_nontemporal_load(cwp + j + 4);
            unsigned c3 = __builtin_nontemporal_load(cwp + j + 6);
            acc = fmaf(h2f(c0 >> 16), bf2f(hbuf[(size_t)(c0 & 0xFFFFu) * 32 + ch]), acc);
            a1  = fmaf(h2f(c1 >> 16), bf2f(hbuf[(size_t)(c1 & 0xFFFFu) * 32 + ch]), a1);
            a2  = fmaf(h2f(c2 >> 16), bf2f(hbuf[(size_t)(c2 & 0xFFFFu) * 32 + ch]), a2);
            a3  = fmaf(h2f(c3 >> 16), bf2f(hbuf[(size_t)(c3 & 0xFFFFu) * 32 + ch]), a3);
        }
        for (; j < end; j += 2) {
            unsigned c = __builtin_nontemporal_load(cwp + j);
            acc = fmaf(h2f(c >> 16), bf2f(hbuf[(size_t)(c & 0xFFFFu) * 32 + ch]), acc);
        }
        acc += (a1 + a2) + a3;
        acc += __shfl_xor(acc, 32, 64);   // both halves hold av[ch]

        if (half == 0) ((float*)&scr[wid][0])[ch] = acc;
        asm volatile("s_waitcnt lgkmcnt(0)" ::: "memory");

        // ---- GEMV: p0z/p0h = av . M2z/M2h (col j=lane) ----
        float p0z = czv, p0h = chv;
        const float4* arow = &scr[wid][0];
        #pragma unroll
        for (int c = 0; c < 8; ++c) {
            float4 av = arow[c];
            float4 w0 = wqs[(2 * c) * 64 + lane];
            float4 w1 = wqs[(2 * c + 1) * 64 + lane];
            p0z = fmaf(av.x, w0.x, p0z); p0h = fmaf(av.x, w0.y, p0h);
            p0z = fmaf(av.y, w0.z, p0z); p0h = fmaf(av.y, w0.w, p0h);
            p0z = fmaf(av.z, w1.x, p0z); p0h = fmaf(av.z, w1.y, p0h);
            p0z = fmaf(av.w, w1.z, p0z); p0h = fmaf(av.w, w1.w, p0h);
        }
        float tt[12] = {bf2f((unsigned short)(tA.x & 0xFFFFu)), bf2f((unsigned short)(tA.x >> 16)),
                        bf2f((unsigned short)(tA.y & 0xFFFFu)), bf2f((unsigned short)(tA.y >> 16)),
                        bf2f((unsigned short)(tB.x & 0xFFFFu)), bf2f((unsigned short)(tB.x >> 16)),
                        bf2f((unsigned short)(tB.y & 0xFFFFu)), bf2f((unsigned short)(tB.y >> 16)),
                        bf2f((unsigned short)(tC.x & 0xFFFFu)), bf2f((unsigned short)(tC.x >> 16)),
                        bf2f((unsigned short)(tC.y & 0xFFFFu)), bf2f((unsigned short)(tC.y >> 16))};
        float acc2 = 0.f;
        #pragma unroll
        for (int p = 0; p < 12; ++p) {
            float t = tt[p];
            float ez = __expf(-fmaf(t, qz, p0z));
            float eh = __expf(-2.f * fmaf(t, qh, p0h));
            float R = __builtin_amdgcn_rcpf((1.f + ez) * (1.f + eh));
            acc2 = fmaf(s_pr[p] * ez * (1.f - eh), R, acc2);
        }
        float h2 = fmaxf(acc2, 0.f);
        ((float*)&scr[wid][0])[lane] = h2;
        asm volatile("s_waitcnt lgkmcnt(0)" ::: "memory");

        // ---- h3 = relu(h2 . lw1 + lb1), split over halves ----
        float h3 = half ? 0.f : lb1v;
        const float4* hrow = &scr[wid][half * 8];
        #pragma unroll
        for (int c = 0; c < 8; ++c) {
            float4 hv = hrow[c];
            int jb = half * 32 + c * 4;
            h3 = fmaf(hv.x, s_lw1[(jb + 0) * 32 + ch], h3);
            h3 = fmaf(hv.y, s_lw1[(jb + 1) * 32 + ch], h3);
            h3 = fmaf(hv.z, s_lw1[(jb + 2) * 32 + ch], h3);
            h3 = fmaf(hv.w, s_lw1[(jb + 3) * 32 + ch], h3);
        }
        h3 += __shfl_xor(h3, 32, 64);
        h3 = fmaxf(h3, 0.f);

        // ---- out = h3 . lw2 + lb2 (lw2 in registers) ----
        float o = lb2v;
        #pragma unroll
        for (int i = 0; i < 8; ++i) {
            float h3k = __shfl(h3, q_ * 8 + i, 64);
            o = fmaf(h3k, wlw2[i], o);
        }
        o += __shfl_xor(o, 16, 64);
        o += __shfl_xor(o, 32, 64);
        if (lane < 12)
            __builtin_nontemporal_store(o, out + (size_t)node * 12 + lane);
    }
}

extern "C" void kernel_launch(void* const* d_in, const int* in_sizes, int n_in,
                              void* d_out, int out_size, void* d_ws, size_t ws_size,
                              hipStream_t stream) {
    const float* x1   = (const float*)d_in[0];
    const int*   eidx = (const int*)d_in[1];
    const float* W1   = (const float*)d_in[4];
    const float* b1   = (const float*)d_in[5];
    const float* Wl1  = (const float*)d_in[6];
    const float* bl1  = (const float*)d_in[7];
    const float* att1 = (const float*)d_in[8];
    const float* W2   = (const float*)d_in[9];
    const float* b2   = (const float*)d_in[10];
    const float* Wl2  = (const float*)d_in[11];
    const float* bl2  = (const float*)d_in[12];
    const float* att2 = (const float*)d_in[13];
    const float* lw1  = (const float*)d_in[14];
    const float* lb1  = (const float*)d_in[15];
    const float* lw2  = (const float*)d_in[16];
    const float* lb2  = (const float*)d_in[17];
    (void)n_in; (void)out_size; (void)ws_size;

    int N = in_sizes[0] / 24;
    int E = in_sizes[1] / 2;
    const int* srcp = eidx;
    const int* dstp = eidx + E;
    int nb = (N + 1023) / 1024;
    int n32 = N * 32;
    int ncb = (n32 / 4 + 255) / 256;        // cvt blocks
    int neb = (E + 255) / 256;              // count blocks

    char* ws = (char*)d_ws;
    size_t off = 0;
    auto alloc = [&](size_t bytes) -> char* {
        char* p = ws + off;
        off += (bytes + 511) & ~(size_t)511;
        return p;
    };
    int*            cnt    = (int*)alloc((size_t)N * 4);
    int*            rowptr = (int*)alloc((size_t)(N + 1) * 4);
    float*          dinv   = (float*)alloc((size_t)N * 4);
    int*            epos   = (int*)alloc((size_t)E * 4);
    unsigned*       cwp    = (unsigned*)alloc((size_t)E * 4);
    unsigned short* x1h    = (unsigned short*)alloc((size_t)n32 * 2);
    unsigned short* hbuf   = (unsigned short*)alloc((size_t)N * 32 * 2);
    unsigned short* atimeh = (unsigned short*)alloc((size_t)N * 12 * 2);
    float*          small  = (float*)alloc(4624 * 4);
    int*            bsum   = (int*)alloc((size_t)nb * 4);
    int*            boffs  = (int*)alloc((size_t)nb * 4);

    (void)hipMemsetAsync(cnt, 0, (size_t)N * 4, stream);
    prep_cvt_count<<<PREPB + ncb + neb, 256, 0, stream>>>(
        x1, x1h, n32, ncb, dstp, cnt, epos, E,
        W1, b1, Wl1, bl1, att1, W2, b2, Wl2, bl2, att2, small);
    scan_blocksum<<<nb, 256, 0, stream>>>(cnt, dinv, bsum, N);
    scan_boffs<<<1, 64, 0, stream>>>(bsum, boffs, rowptr, nb, N);
    scan_write<<<nb, 256, 0, stream>>>(cnt, boffs, rowptr, N);
    scatter_edges<<<neb, 256, 0, stream>>>(srcp, dstp, epos, dinv, rowptr, cwp, E);
    agg1_layer1<<<(N * 32 + 255) / 256, 256, 0, stream>>>(x1, x1h, rowptr, cwp, dinv, small, hbuf, atimeh, N);
    agg2_layer2<<<1024, 512, 0, stream>>>(hbuf, atimeh, rowptr, cwp, dinv, small,
                                          lw1, lb1, lw2, lb2, (float*)d_out, N);
}

// Round 20
// 151.119 us; speedup vs baseline: 3.4877x; 1.0353x over previous
//
#include <hip/hip_runtime.h>
#include <hip/hip_bf16.h>
#include <hip/hip_fp16.h>
#include <math.h>

// ---------------------------------------------------------------------------
// A3T-GCN two-layer, restructured (see round-1 notes):
//   - H == 0 => R gate dead, cell = (1-Z)*tanh(...)
//   - A_hat commutes with W => one propagation per layer, folded gate matrices
//   - layer2 time channel reuses layer-1 propagation (rank-1 per period)
// Round 20: (a) count + scatter vectorized to 4 edges/thread (int4 streams,
// 4 independent atomic/pointer chains in flight); (b) scan_boffs folded into
// scan_write (each block one-wave-scans the <=64 bsums itself) - one launch
// removed. agg1/agg2 and the rest identical to round 19 (156.5 us).
// ---------------------------------------------------------------------------

typedef float f4v __attribute__((ext_vector_type(4)));
typedef unsigned u2v __attribute__((ext_vector_type(2)));
typedef int i4v __attribute__((ext_vector_type(4)));

#define PREPB 17  // prep block range at the head of prep_cvt_count

static __device__ __forceinline__ unsigned short f2bf(float f) {
    unsigned u = __float_as_uint(f);
    unsigned r = (u + 0x7FFFu + ((u >> 16) & 1u)) >> 16;  // RNE
    return (unsigned short)r;
}
static __device__ __forceinline__ float bf2f(unsigned short u) {
    return __uint_as_float(((unsigned)u) << 16);
}
static __device__ __forceinline__ unsigned short f2h(float f) {
    __half h = __float2half_rn(f);
    return *reinterpret_cast<unsigned short*>(&h);
}
static __device__ __forceinline__ float h2f(unsigned short u) {
    __half h;
    *reinterpret_cast<unsigned short*>(&h) = u;
    return __half2float(h);
}

// small[] layout (floats):
//   [0:32)a0z [32:64)a1z [64:96)c1z [96:128)a0h [128:160)a1h [160:192)c1h [192:204)probs1
//   [256:2304) M2z   [2304:4352) M2h
//   [4352:4416) q2z [4416:4480) q2h [4480:4544) c2z [4544:4608) c2h [4608:4620) probs2
// blocks [0,PREPB): weight folding. blocks [PREPB,PREPB+ncb): x1 -> bf16
// padded rows. blocks [PREPB+ncb,...): count 4 edges/thread -> epos.
__global__ void prep_cvt_count(
    const float* __restrict__ in, unsigned short* __restrict__ outh,
    int n32, int ncb,
    const int* __restrict__ dst, int* __restrict__ cnt,
    int* __restrict__ epos, int E,
    const float* __restrict__ W1, const float* __restrict__ b1,
    const float* __restrict__ Wl1, const float* __restrict__ bl1,
    const float* __restrict__ att1,
    const float* __restrict__ W2, const float* __restrict__ b2,
    const float* __restrict__ Wl2, const float* __restrict__ bl2,
    const float* __restrict__ att2, float* __restrict__ small) {
    int tid = threadIdx.x;
    if ((int)blockIdx.x < PREPB) {
        if (blockIdx.x == 0) {
            if (tid < 192) {  // layer-1 folds
                int which = tid >> 5, hh = tid & 31;
                int g = (which < 3) ? 0 : 2;
                int kind = which % 3;  // 0:a0 1:a1 2:c
                const float* Wl = Wl1 + g * 64 * 32;
                float s = 0.f;
                if (kind < 2) {
                    const float* Wr = W1 + g * 2 * 32 + kind * 32;
                    for (int k = 0; k < 32; ++k) s += Wr[k] * Wl[k * 32 + hh];
                } else {
                    const float* br = b1 + g * 32;
                    for (int k = 0; k < 32; ++k) s += br[k] * Wl[k * 32 + hh];
                    s += bl1[g * 32 + hh];
                }
                small[tid] = s;
            }
            {  // q (time row) and c (bias) folds: 256 outputs
                int which = tid >> 6, j = tid & 63;
                int g = (which == 0 || which == 2) ? 0 : 2;
                const float* Wl = Wl2 + g * 128 * 64;
                float s = 0.f;
                if (which < 2) {
                    const float* Wr = W2 + g * 33 * 64 + 32 * 64;
                    for (int k = 0; k < 64; ++k) s += Wr[k] * Wl[k * 64 + j];
                } else {
                    const float* br = b2 + g * 64;
                    for (int k = 0; k < 64; ++k) s += br[k] * Wl[k * 64 + j];
                    s += bl2[g * 64 + j];
                }
                small[4352 + tid] = s;
            }
            if (tid == 0) {  // softmax(att1)
                float mx = att1[0];
                for (int p = 1; p < 12; ++p) mx = fmaxf(mx, att1[p]);
                float e[12], sm = 0.f;
                for (int p = 0; p < 12; ++p) { e[p] = expf(att1[p] - mx); sm += e[p]; }
                for (int p = 0; p < 12; ++p) small[192 + p] = e[p] / sm;
            } else if (tid == 1) {  // softmax(att2)
                float mx = att2[0];
                for (int p = 1; p < 12; ++p) mx = fmaxf(mx, att2[p]);
                float e[12], sm = 0.f;
                for (int p = 0; p < 12; ++p) { e[p] = expf(att2[p] - mx); sm += e[p]; }
                for (int p = 0; p < 12; ++p) small[4608 + p] = e[p] / sm;
            }
        } else {  // blocks 1..16: M2 fold, t in [0,4096)
            int t = (blockIdx.x - 1) * 256 + tid;
            int gg = t >> 11;
            int rem = t & 2047;
            int i = rem >> 6, j = rem & 63;
            int g = gg ? 2 : 0;
            const float* Wl = Wl2 + g * 128 * 64;
            const float* Wr = W2 + g * 33 * 64 + i * 64;
            float s = 0.f;
            for (int k = 0; k < 64; ++k) s += Wr[k] * Wl[k * 64 + j];
            small[256 + gg * 2048 + i * 64 + j] = s;
        }
    } else if ((int)blockIdx.x < PREPB + ncb) {
        int i = ((blockIdx.x - PREPB) * blockDim.x + tid) * 4;
        if (i < n32) {
            int node = i >> 5, c = i & 31;
            const float* row = in + (size_t)node * 24;
            ushort4 u;
            u.x = (c + 0 < 24) ? f2bf(__builtin_nontemporal_load(row + c + 0)) : (unsigned short)0;
            u.y = (c + 1 < 24) ? f2bf(__builtin_nontemporal_load(row + c + 1)) : (unsigned short)0;
            u.z = (c + 2 < 24) ? f2bf(__builtin_nontemporal_load(row + c + 2)) : (unsigned short)0;
            u.w = (c + 3 < 24) ? f2bf(__builtin_nontemporal_load(row + c + 3)) : (unsigned short)0;
            *(ushort4*)(outh + i) = u;
        }
    } else {
        int e = (((int)blockIdx.x - PREPB - ncb) * blockDim.x + tid) * 4;
        if (e + 3 < E) {
            i4v d4 = __builtin_nontemporal_load((const i4v*)(dst + e));
            i4v p4;
            p4.x = atomicAdd(&cnt[d4.x], 1);
            p4.y = atomicAdd(&cnt[d4.y], 1);
            p4.z = atomicAdd(&cnt[d4.z], 1);
            p4.w = atomicAdd(&cnt[d4.w], 1);
            __builtin_nontemporal_store(p4, (i4v*)(epos + e));
        } else {
            for (int k = 0; k < 4; ++k)
                if (e + k < E) {
                    int d = dst[e + k];
                    epos[e + k] = atomicAdd(&cnt[d], 1);
                }
        }
    }
}

// --- parallel exclusive scan of cnt -> rowptr, plus dinv ------------------
__global__ __launch_bounds__(256) void scan_blocksum(
    const int* __restrict__ cnt, float* __restrict__ dinv,
    int* __restrict__ bsum, int n) {
    int base = blockIdx.x * 1024 + threadIdx.x * 4;
    int s = 0;
    if (base + 3 < n) {
        int4 v = *(const int4*)(cnt + base);
        dinv[base + 0] = rsqrtf((float)v.x + 1.f);
        dinv[base + 1] = rsqrtf((float)v.y + 1.f);
        dinv[base + 2] = rsqrtf((float)v.z + 1.f);
        dinv[base + 3] = rsqrtf((float)v.w + 1.f);
        s = v.x + v.y + v.z + v.w;
    } else {
        for (int k = 0; k < 4; ++k)
            if (base + k < n) {
                int v = cnt[base + k];
                dinv[base + k] = rsqrtf((float)v + 1.f);
                s += v;
            }
    }
    #pragma unroll
    for (int off = 32; off > 0; off >>= 1) s += __shfl_down(s, off, 64);
    __shared__ int ws[4];
    int lane = threadIdx.x & 63, wid = threadIdx.x >> 6;
    if (lane == 0) ws[wid] = s;
    __syncthreads();
    if (threadIdx.x == 0) bsum[blockIdx.x] = ws[0] + ws[1] + ws[2] + ws[3];
}

// scan_write with inlined block-offset scan: wave 0 scans bsum (<=64/chunk)
// to derive this block's exclusive offset; block 0 also writes rowptr[n].
__global__ __launch_bounds__(256) void scan_write(
    const int* __restrict__ cnt, const int* __restrict__ bsum, int nb,
    int* __restrict__ rowptr, int n) {
    __shared__ int s_boff, s_total;
    int lane = threadIdx.x & 63, wid = threadIdx.x >> 6;
    if (threadIdx.x < 64) {
        int carry = 0;
        for (int base = 0; base < nb; base += 64) {
            int i = base + lane;
            int v = (i < nb) ? bsum[i] : 0;
            int orig = v;
            #pragma unroll
            for (int off = 1; off < 64; off <<= 1) {
                int t = __shfl_up(v, off, 64);
                if (lane >= off) v += t;
            }
            if (i == (int)blockIdx.x) s_boff = carry + v - orig;  // exclusive
            carry += __shfl(v, 63, 64);
        }
        if (lane == 0) s_total = carry;
    }
    int base = blockIdx.x * 1024 + threadIdx.x * 4;
    int4 v = make_int4(0, 0, 0, 0);
    if (base + 3 < n) {
        v = *(const int4*)(cnt + base);
    } else {
        if (base + 0 < n) v.x = cnt[base + 0];
        if (base + 1 < n) v.y = cnt[base + 1];
        if (base + 2 < n) v.z = cnt[base + 2];
        if (base + 3 < n) v.w = cnt[base + 3];
    }
    int t0 = v.x, t1 = t0 + v.y, t2 = t1 + v.z, t3 = t2 + v.w;  // inclusive
    int sc = t3;
    #pragma unroll
    for (int off = 1; off < 64; off <<= 1) {
        int t = __shfl_up(sc, off, 64);
        if (lane >= off) sc += t;
    }
    __shared__ int ws[4];
    if (lane == 63) ws[wid] = sc;
    __syncthreads();
    int woff = 0;
    for (int w = 0; w < wid; ++w) woff += ws[w];
    int off0 = s_boff + woff + sc - t3;  // exclusive at base
    if (base + 3 < n) {
        *(int4*)(rowptr + base) = make_int4(off0, off0 + t0, off0 + t1, off0 + t2);
    } else {
        if (base + 0 < n) rowptr[base + 0] = off0;
        if (base + 1 < n) rowptr[base + 1] = off0 + t0;
        if (base + 2 < n) rowptr[base + 2] = off0 + t1;
        if (base + 3 < n) rowptr[base + 3] = off0 + t2;
    }
    if (blockIdx.x == 0 && threadIdx.x == 0) rowptr[n] = s_total;
}

// Atomic-free scatter, 4 edges/thread: slot = rowptr[d] + epos[e].
__global__ void scatter_edges(const int* __restrict__ src, const int* __restrict__ dst,
                              const int* __restrict__ epos,
                              const float* __restrict__ dinv, const int* __restrict__ rowptr,
                              unsigned* __restrict__ cwp, int E) {
    int e = (blockIdx.x * blockDim.x + threadIdx.x) * 4;
    if (e + 3 < E) {
        i4v s4 = __builtin_nontemporal_load((const i4v*)(src + e));
        i4v d4 = __builtin_nontemporal_load((const i4v*)(dst + e));
        i4v p4 = __builtin_nontemporal_load((const i4v*)(epos + e));
        int i0 = rowptr[d4.x] + p4.x;
        int i1 = rowptr[d4.y] + p4.y;
        int i2 = rowptr[d4.z] + p4.z;
        int i3 = rowptr[d4.w] + p4.w;
        float dd0 = dinv[d4.x], dd1 = dinv[d4.y], dd2 = dinv[d4.z], dd3 = dinv[d4.w];
        unsigned pk0 = (unsigned)(unsigned short)s4.x | ((unsigned)f2h(dinv[s4.x] * dd0) << 16);
        unsigned pk1 = (unsigned)(unsigned short)s4.y | ((unsigned)f2h(dinv[s4.y] * dd1) << 16);
        unsigned pk2 = (unsigned)(unsigned short)s4.z | ((unsigned)f2h(dinv[s4.z] * dd2) << 16);
        unsigned pk3 = (unsigned)(unsigned short)s4.w | ((unsigned)f2h(dinv[s4.w] * dd3) << 16);
        __builtin_nontemporal_store(pk0, cwp + i0);
        __builtin_nontemporal_store(pk1, cwp + i1);
        __builtin_nontemporal_store(pk2, cwp + i2);
        __builtin_nontemporal_store(pk3, cwp + i3);
    } else {
        for (int k = 0; k < 4; ++k)
            if (e + k < E) {
                int s = src[e + k], d = dst[e + k];
                int idx = rowptr[d] + epos[e + k];
                float w = dinv[s] * dinv[d];
                cwp[idx] = (unsigned)(unsigned short)s | ((unsigned)f2h(w) << 16);
            }
    }
}

// One 32-lane group per node. Lanes 0..23 aggregate A_hat x1 (24 ch);
// gathers from padded [N][32] bf16 rows (one 64B line per edge).
// Gates use the one-rcp fused form (validated in agg2): no tanhf/div.
__global__ __launch_bounds__(256) void agg1_layer1(
    const float* __restrict__ X, const unsigned short* __restrict__ Xh,
    const int* __restrict__ rowptr, const unsigned* __restrict__ cwp,
    const float* __restrict__ dinv, const float* __restrict__ small,
    unsigned short* __restrict__ hout, unsigned short* __restrict__ atimeh, int n) {
    int lane = threadIdx.x & 31;
    int node = (blockIdx.x * blockDim.x + threadIdx.x) >> 5;
    if (node >= n) return;
    int beg = rowptr[node], end = rowptr[node + 1];
    float acc = 0.f;
    if (lane < 24) {
        float dn = dinv[node];
        acc = dn * dn * __builtin_nontemporal_load(X + (size_t)node * 24 + lane);
        float a0 = 0.f, a1 = 0.f, a2 = 0.f, a3 = 0.f;
        int j = beg;
        for (; j + 4 <= end; j += 4) {
            unsigned c0 = __builtin_nontemporal_load(cwp + j);
            unsigned c1 = __builtin_nontemporal_load(cwp + j + 1);
            unsigned c2 = __builtin_nontemporal_load(cwp + j + 2);
            unsigned c3 = __builtin_nontemporal_load(cwp + j + 3);
            a0 = fmaf(h2f(c0 >> 16), bf2f(Xh[(c0 & 0xFFFFu) * 32 + lane]), a0);
            a1 = fmaf(h2f(c1 >> 16), bf2f(Xh[(c1 & 0xFFFFu) * 32 + lane]), a1);
            a2 = fmaf(h2f(c2 >> 16), bf2f(Xh[(c2 & 0xFFFFu) * 32 + lane]), a2);
            a3 = fmaf(h2f(c3 >> 16), bf2f(Xh[(c3 & 0xFFFFu) * 32 + lane]), a3);
        }
        for (; j < end; ++j) {
            unsigned c = __builtin_nontemporal_load(cwp + j);
            acc = fmaf(h2f(c >> 16), bf2f(Xh[(c & 0xFFFFu) * 32 + lane]), acc);
        }
        acc += (a0 + a1) + (a2 + a3);
    }
    if (lane >= 12 && lane < 24)
        atimeh[(size_t)node * 12 + lane - 12] = f2bf(acc);
    float a0z = small[lane], a1z = small[32 + lane], c1z = small[64 + lane];
    float a0h = small[96 + lane], a1h = small[128 + lane], c1h = small[160 + lane];
    float hs = 0.f;
    #pragma unroll
    for (int p = 0; p < 12; ++p) {
        float x0 = __shfl(acc, p, 32);
        float x1 = __shfl(acc, 12 + p, 32);
        float ez = __expf(-fmaf(x0, a0z, fmaf(x1, a1z, c1z)));
        float eh = __expf(-2.f * fmaf(x0, a0h, fmaf(x1, a1h, c1h)));
        float R = __builtin_amdgcn_rcpf((1.f + ez) * (1.f + eh));
        hs = fmaf(small[192 + p] * ez * (1.f - eh), R, hs);
    }
    hout[(size_t)node * 32 + lane] = f2bf(fmaxf(hs, 0.f));
}

// Fused agg2 + layer2 + final MLP. One 64-lane wave per node; 8 waves/block
// share the LDS weight tiles -> 4 blocks/CU = 32 waves/CU. Grid 1024 = one
// resident generation, static grid-stride.
__global__ __launch_bounds__(512, 8) void agg2_layer2(
    const unsigned short* __restrict__ hbuf, const unsigned short* __restrict__ atimeh,
    const int* __restrict__ rowptr, const unsigned* __restrict__ cwp,
    const float* __restrict__ dinv, const float* __restrict__ small,
    const float* __restrict__ lw1, const float* __restrict__ lb1,
    const float* __restrict__ lw2, const float* __restrict__ lb2,
    float* __restrict__ out, int n) {
    __shared__ __align__(16) float4 wqs[1024];          // 16 KB M2z/M2h interleaved
    __shared__ __align__(16) float s_lw1[2048];          // 8 KB [j][k] 64x32
    __shared__ float s_pr[16];
    __shared__ __align__(16) float4 scr[8][16];          // per-wave av/h2 scratch

    for (int t = threadIdx.x; t < 4096; t += 512) {
        int s = t & 3, j = (t >> 2) & 63, k2 = t >> 8;
        int k = 2 * k2 + (s >> 1), zh = s & 1;
        ((float*)wqs)[t] = small[256 + zh * 2048 + k * 64 + j];
    }
    for (int t = threadIdx.x; t < 2048; t += 512) s_lw1[t] = lw1[t];
    if (threadIdx.x < 16) s_pr[threadIdx.x] = (threadIdx.x < 12) ? small[4608 + threadIdx.x] : 0.f;
    __syncthreads();

    int lane = threadIdx.x & 63;
    int wid = threadIdx.x >> 6;
    int ch = lane & 31, half = lane >> 5;
    float qz = small[4352 + lane], qh = small[4416 + lane];
    float czv = small[4480 + lane], chv = small[4544 + lane];
    float lb1v = lb1[ch];
    int p_ = lane & 15, q_ = lane >> 4;
    float lb2v = (q_ == 0 && p_ < 12) ? lb2[p_] : 0.f;
    float wlw2[8];
    #pragma unroll
    for (int i = 0; i < 8; ++i)
        wlw2[i] = (p_ < 12) ? lw2[(q_ * 8 + i) * 12 + p_] : 0.f;

    int totalw = gridDim.x * 8;
    for (int node = blockIdx.x * 8 + wid; node < n; node += totalw) {
        // early-issue the independent atime row (hides under gather)
        const u2v* trow = (const u2v*)(atimeh + (size_t)node * 12);
        u2v tA = __builtin_nontemporal_load(trow);
        u2v tB = __builtin_nontemporal_load(trow + 1);
        u2v tC = __builtin_nontemporal_load(trow + 2);

        // ---- fused agg2: av[ch] = (A_hat h)[node][ch], bf16 gather ----
        int beg = rowptr[node], end = rowptr[node + 1];
        float dn = dinv[node];
        float acc = (half == 0) ? dn * dn * bf2f(hbuf[(size_t)node * 32 + ch]) : 0.f;
        float a1 = 0.f, a2 = 0.f, a3 = 0.f;
        int j = beg + half;
        for (; j + 6 < end; j += 8) {
            unsigned c0 = __builtin_nontemporal_load(cwp + j);
            unsigned c1 = __builtin_nontemporal_load(cwp + j + 2);
            unsigned c2 = __builtin_nontemporal_load(cwp + j + 4);
            unsigned c3 = __builtin_nontemporal_load(cwp + j + 6);
            acc = fmaf(h2f(c0 >> 16), bf2f(hbuf[(size_t)(c0 & 0xFFFFu) * 32 + ch]), acc);
            a1  = fmaf(h2f(c1 >> 16), bf2f(hbuf[(size_t)(c1 & 0xFFFFu) * 32 + ch]), a1);
            a2  = fmaf(h2f(c2 >> 16), bf2f(hbuf[(size_t)(c2 & 0xFFFFu) * 32 + ch]), a2);
            a3  = fmaf(h2f(c3 >> 16), bf2f(hbuf[(size_t)(c3 & 0xFFFFu) * 32 + ch]), a3);
        }
        for (; j < end; j += 2) {
            unsigned c = __builtin_nontemporal_load(cwp + j);
            acc = fmaf(h2f(c >> 16), bf2f(hbuf[(size_t)(c & 0xFFFFu) * 32 + ch]), acc);
        }
        acc += (a1 + a2) + a3;
        acc += __shfl_xor(acc, 32, 64);   // both halves hold av[ch]

        if (half == 0) ((float*)&scr[wid][0])[ch] = acc;
        asm volatile("s_waitcnt lgkmcnt(0)" ::: "memory");

        // ---- GEMV: p0z/p0h = av . M2z/M2h (col j=lane) ----
        float p0z = czv, p0h = chv;
        const float4* arow = &scr[wid][0];
        #pragma unroll
        for (int c = 0; c < 8; ++c) {
            float4 av = arow[c];
            float4 w0 = wqs[(2 * c) * 64 + lane];
            float4 w1 = wqs[(2 * c + 1) * 64 + lane];
            p0z = fmaf(av.x, w0.x, p0z); p0h = fmaf(av.x, w0.y, p0h);
            p0z = fmaf(av.y, w0.z, p0z); p0h = fmaf(av.y, w0.w, p0h);
            p0z = fmaf(av.z, w1.x, p0z); p0h = fmaf(av.z, w1.y, p0h);
            p0z = fmaf(av.w, w1.z, p0z); p0h = fmaf(av.w, w1.w, p0h);
        }
        float tt[12] = {bf2f((unsigned short)(tA.x & 0xFFFFu)), bf2f((unsigned short)(tA.x >> 16)),
                        bf2f((unsigned short)(tA.y & 0xFFFFu)), bf2f((unsigned short)(tA.y >> 16)),
                        bf2f((unsigned short)(tB.x & 0xFFFFu)), bf2f((unsigned short)(tB.x >> 16)),
                        bf2f((unsigned short)(tB.y & 0xFFFFu)), bf2f((unsigned short)(tB.y >> 16)),
                        bf2f((unsigned short)(tC.x & 0xFFFFu)), bf2f((unsigned short)(tC.x >> 16)),
                        bf2f((unsigned short)(tC.y & 0xFFFFu)), bf2f((unsigned short)(tC.y >> 16))};
        float acc2 = 0.f;
        #pragma unroll
        for (int p = 0; p < 12; ++p) {
            float t = tt[p];
            float ez = __expf(-fmaf(t, qz, p0z));
            float eh = __expf(-2.f * fmaf(t, qh, p0h));
            float R = __builtin_amdgcn_rcpf((1.f + ez) * (1.f + eh));
            acc2 = fmaf(s_pr[p] * ez * (1.f - eh), R, acc2);
        }
        float h2 = fmaxf(acc2, 0.f);
        ((float*)&scr[wid][0])[lane] = h2;
        asm volatile("s_waitcnt lgkmcnt(0)" ::: "memory");

        // ---- h3 = relu(h2 . lw1 + lb1), split over halves ----
        float h3 = half ? 0.f : lb1v;
        const float4* hrow = &scr[wid][half * 8];
        #pragma unroll
        for (int c = 0; c < 8; ++c) {
            float4 hv = hrow[c];
            int jb = half * 32 + c * 4;
            h3 = fmaf(hv.x, s_lw1[(jb + 0) * 32 + ch], h3);
            h3 = fmaf(hv.y, s_lw1[(jb + 1) * 32 + ch], h3);
            h3 = fmaf(hv.z, s_lw1[(jb + 2) * 32 + ch], h3);
            h3 = fmaf(hv.w, s_lw1[(jb + 3) * 32 + ch], h3);
        }
        h3 += __shfl_xor(h3, 32, 64);
        h3 = fmaxf(h3, 0.f);

        // ---- out = h3 . lw2 + lb2 (lw2 in registers) ----
        float o = lb2v;
        #pragma unroll
        for (int i = 0; i < 8; ++i) {
            float h3k = __shfl(h3, q_ * 8 + i, 64);
            o = fmaf(h3k, wlw2[i], o);
        }
        o += __shfl_xor(o, 16, 64);
        o += __shfl_xor(o, 32, 64);
        if (lane < 12)
            __builtin_nontemporal_store(o, out + (size_t)node * 12 + lane);
    }
}

extern "C" void kernel_launch(void* const* d_in, const int* in_sizes, int n_in,
                              void* d_out, int out_size, void* d_ws, size_t ws_size,
                              hipStream_t stream) {
    const float* x1   = (const float*)d_in[0];
    const int*   eidx = (const int*)d_in[1];
    const float* W1   = (const float*)d_in[4];
    const float* b1   = (const float*)d_in[5];
    const float* Wl1  = (const float*)d_in[6];
    const float* bl1  = (const float*)d_in[7];
    const float* att1 = (const float*)d_in[8];
    const float* W2   = (const float*)d_in[9];
    const float* b2   = (const float*)d_in[10];
    const float* Wl2  = (const float*)d_in[11];
    const float* bl2  = (const float*)d_in[12];
    const float* att2 = (const float*)d_in[13];
    const float* lw1  = (const float*)d_in[14];
    const float* lb1  = (const float*)d_in[15];
    const float* lw2  = (const float*)d_in[16];
    const float* lb2  = (const float*)d_in[17];
    (void)n_in; (void)out_size; (void)ws_size;

    int N = in_sizes[0] / 24;
    int E = in_sizes[1] / 2;
    const int* srcp = eidx;
    const int* dstp = eidx + E;
    int nb = (N + 1023) / 1024;
    int n32 = N * 32;
    int ncb = (n32 / 4 + 255) / 256;        // cvt blocks
    int neb4 = ((E + 3) / 4 + 255) / 256;   // count blocks (4 edges/thread)

    char* ws = (char*)d_ws;
    size_t off = 0;
    auto alloc = [&](size_t bytes) -> char* {
        char* p = ws + off;
        off += (bytes + 511) & ~(size_t)511;
        return p;
    };
    int*            cnt    = (int*)alloc((size_t)N * 4);
    int*            rowptr = (int*)alloc((size_t)(N + 1) * 4);
    float*          dinv   = (float*)alloc((size_t)N * 4);
    int*            epos   = (int*)alloc((size_t)E * 4);
    unsigned*       cwp    = (unsigned*)alloc((size_t)E * 4);
    unsigned short* x1h    = (unsigned short*)alloc((size_t)n32 * 2);
    unsigned short* hbuf   = (unsigned short*)alloc((size_t)N * 32 * 2);
    unsigned short* atimeh = (unsigned short*)alloc((size_t)N * 12 * 2);
    float*          small  = (float*)alloc(4624 * 4);
    int*            bsum   = (int*)alloc((size_t)nb * 4);

    (void)hipMemsetAsync(cnt, 0, (size_t)N * 4, stream);
    prep_cvt_count<<<PREPB + ncb + neb4, 256, 0, stream>>>(
        x1, x1h, n32, ncb, dstp, cnt, epos, E,
        W1, b1, Wl1, bl1, att1, W2, b2, Wl2, bl2, att2, small);
    scan_blocksum<<<nb, 256, 0, stream>>>(cnt, dinv, bsum, N);
    scan_write<<<nb, 256, 0, stream>>>(cnt, bsum, nb, rowptr, N);
    scatter_edges<<<neb4, 256, 0, stream>>>(srcp, dstp, epos, dinv, rowptr, cwp, E);
    agg1_layer1<<<(N * 32 + 255) / 256, 256, 0, stream>>>(x1, x1h, rowptr, cwp, dinv, small, hbuf, atimeh, N);
    agg2_layer2<<<1024, 512, 0, stream>>>(hbuf, atimeh, rowptr, cwp, dinv, small,
                                          lw1, lb1, lw2, lb2, (float*)d_out, N);
}

// Round 21
// 148.419 us; speedup vs baseline: 3.5512x; 1.0182x over previous
//
#include <hip/hip_runtime.h>
#include <hip/hip_bf16.h>
#include <hip/hip_fp16.h>
#include <math.h>

// ---------------------------------------------------------------------------
// A3T-GCN two-layer, restructured (see round-1 notes):
//   - H == 0 => R gate dead, cell = (1-Z)*tanh(...)
//   - A_hat commutes with W => one propagation per layer, folded gate matrices
//   - layer2 time channel reuses layer-1 propagation (rank-1 per period)
// Round 21: agg2 gather remapped to 4 edge-groups x 16 lanes, each lane
// loading u32 = 2 bf16 channels (halves lane-loads per edge; unpack is
// shl/and only). Combine via shfl_xor(16/32); lanes 0-15 write av pairs.
// GEMV/gates unchanged. Rest identical to round 20 (151.1 us).
// ---------------------------------------------------------------------------

typedef float f4v __attribute__((ext_vector_type(4)));
typedef unsigned u2v __attribute__((ext_vector_type(2)));
typedef int i4v __attribute__((ext_vector_type(4)));

#define PREPB 17  // prep block range at the head of prep_cvt_count

static __device__ __forceinline__ unsigned short f2bf(float f) {
    unsigned u = __float_as_uint(f);
    unsigned r = (u + 0x7FFFu + ((u >> 16) & 1u)) >> 16;  // RNE
    return (unsigned short)r;
}
static __device__ __forceinline__ float bf2f(unsigned short u) {
    return __uint_as_float(((unsigned)u) << 16);
}
static __device__ __forceinline__ float bflo(unsigned v) {
    return __uint_as_float(v << 16);
}
static __device__ __forceinline__ float bfhi(unsigned v) {
    return __uint_as_float(v & 0xFFFF0000u);
}
static __device__ __forceinline__ unsigned short f2h(float f) {
    __half h = __float2half_rn(f);
    return *reinterpret_cast<unsigned short*>(&h);
}
static __device__ __forceinline__ float h2f(unsigned short u) {
    __half h;
    *reinterpret_cast<unsigned short*>(&h) = u;
    return __half2float(h);
}

// small[] layout (floats):
//   [0:32)a0z [32:64)a1z [64:96)c1z [96:128)a0h [128:160)a1h [160:192)c1h [192:204)probs1
//   [256:2304) M2z   [2304:4352) M2h
//   [4352:4416) q2z [4416:4480) q2h [4480:4544) c2z [4544:4608) c2h [4608:4620) probs2
__global__ void prep_cvt_count(
    const float* __restrict__ in, unsigned short* __restrict__ outh,
    int n32, int ncb,
    const int* __restrict__ dst, int* __restrict__ cnt,
    int* __restrict__ epos, int E,
    const float* __restrict__ W1, const float* __restrict__ b1,
    const float* __restrict__ Wl1, const float* __restrict__ bl1,
    const float* __restrict__ att1,
    const float* __restrict__ W2, const float* __restrict__ b2,
    const float* __restrict__ Wl2, const float* __restrict__ bl2,
    const float* __restrict__ att2, float* __restrict__ small) {
    int tid = threadIdx.x;
    if ((int)blockIdx.x < PREPB) {
        if (blockIdx.x == 0) {
            if (tid < 192) {  // layer-1 folds
                int which = tid >> 5, hh = tid & 31;
                int g = (which < 3) ? 0 : 2;
                int kind = which % 3;  // 0:a0 1:a1 2:c
                const float* Wl = Wl1 + g * 64 * 32;
                float s = 0.f;
                if (kind < 2) {
                    const float* Wr = W1 + g * 2 * 32 + kind * 32;
                    for (int k = 0; k < 32; ++k) s += Wr[k] * Wl[k * 32 + hh];
                } else {
                    const float* br = b1 + g * 32;
                    for (int k = 0; k < 32; ++k) s += br[k] * Wl[k * 32 + hh];
                    s += bl1[g * 32 + hh];
                }
                small[tid] = s;
            }
            {  // q (time row) and c (bias) folds: 256 outputs
                int which = tid >> 6, j = tid & 63;
                int g = (which == 0 || which == 2) ? 0 : 2;
                const float* Wl = Wl2 + g * 128 * 64;
                float s = 0.f;
                if (which < 2) {
                    const float* Wr = W2 + g * 33 * 64 + 32 * 64;
                    for (int k = 0; k < 64; ++k) s += Wr[k] * Wl[k * 64 + j];
                } else {
                    const float* br = b2 + g * 64;
                    for (int k = 0; k < 64; ++k) s += br[k] * Wl[k * 64 + j];
                    s += bl2[g * 64 + j];
                }
                small[4352 + tid] = s;
            }
            if (tid == 0) {  // softmax(att1)
                float mx = att1[0];
                for (int p = 1; p < 12; ++p) mx = fmaxf(mx, att1[p]);
                float e[12], sm = 0.f;
                for (int p = 0; p < 12; ++p) { e[p] = expf(att1[p] - mx); sm += e[p]; }
                for (int p = 0; p < 12; ++p) small[192 + p] = e[p] / sm;
            } else if (tid == 1) {  // softmax(att2)
                float mx = att2[0];
                for (int p = 1; p < 12; ++p) mx = fmaxf(mx, att2[p]);
                float e[12], sm = 0.f;
                for (int p = 0; p < 12; ++p) { e[p] = expf(att2[p] - mx); sm += e[p]; }
                for (int p = 0; p < 12; ++p) small[4608 + p] = e[p] / sm;
            }
        } else {  // blocks 1..16: M2 fold, t in [0,4096)
            int t = (blockIdx.x - 1) * 256 + tid;
            int gg = t >> 11;
            int rem = t & 2047;
            int i = rem >> 6, j = rem & 63;
            int g = gg ? 2 : 0;
            const float* Wl = Wl2 + g * 128 * 64;
            const float* Wr = W2 + g * 33 * 64 + i * 64;
            float s = 0.f;
            for (int k = 0; k < 64; ++k) s += Wr[k] * Wl[k * 64 + j];
            small[256 + gg * 2048 + i * 64 + j] = s;
        }
    } else if ((int)blockIdx.x < PREPB + ncb) {
        int i = ((blockIdx.x - PREPB) * blockDim.x + tid) * 4;
        if (i < n32) {
            int node = i >> 5, c = i & 31;
            const float* row = in + (size_t)node * 24;
            ushort4 u;
            u.x = (c + 0 < 24) ? f2bf(__builtin_nontemporal_load(row + c + 0)) : (unsigned short)0;
            u.y = (c + 1 < 24) ? f2bf(__builtin_nontemporal_load(row + c + 1)) : (unsigned short)0;
            u.z = (c + 2 < 24) ? f2bf(__builtin_nontemporal_load(row + c + 2)) : (unsigned short)0;
            u.w = (c + 3 < 24) ? f2bf(__builtin_nontemporal_load(row + c + 3)) : (unsigned short)0;
            *(ushort4*)(outh + i) = u;
        }
    } else {
        int e = (((int)blockIdx.x - PREPB - ncb) * blockDim.x + tid) * 4;
        if (e + 3 < E) {
            i4v d4 = __builtin_nontemporal_load((const i4v*)(dst + e));
            i4v p4;
            p4.x = atomicAdd(&cnt[d4.x], 1);
            p4.y = atomicAdd(&cnt[d4.y], 1);
            p4.z = atomicAdd(&cnt[d4.z], 1);
            p4.w = atomicAdd(&cnt[d4.w], 1);
            __builtin_nontemporal_store(p4, (i4v*)(epos + e));
        } else {
            for (int k = 0; k < 4; ++k)
                if (e + k < E) {
                    int d = dst[e + k];
                    epos[e + k] = atomicAdd(&cnt[d], 1);
                }
        }
    }
}

// --- parallel exclusive scan of cnt -> rowptr, plus dinv ------------------
__global__ __launch_bounds__(256) void scan_blocksum(
    const int* __restrict__ cnt, float* __restrict__ dinv,
    int* __restrict__ bsum, int n) {
    int base = blockIdx.x * 1024 + threadIdx.x * 4;
    int s = 0;
    if (base + 3 < n) {
        int4 v = *(const int4*)(cnt + base);
        dinv[base + 0] = rsqrtf((float)v.x + 1.f);
        dinv[base + 1] = rsqrtf((float)v.y + 1.f);
        dinv[base + 2] = rsqrtf((float)v.z + 1.f);
        dinv[base + 3] = rsqrtf((float)v.w + 1.f);
        s = v.x + v.y + v.z + v.w;
    } else {
        for (int k = 0; k < 4; ++k)
            if (base + k < n) {
                int v = cnt[base + k];
                dinv[base + k] = rsqrtf((float)v + 1.f);
                s += v;
            }
    }
    #pragma unroll
    for (int off = 32; off > 0; off >>= 1) s += __shfl_down(s, off, 64);
    __shared__ int ws[4];
    int lane = threadIdx.x & 63, wid = threadIdx.x >> 6;
    if (lane == 0) ws[wid] = s;
    __syncthreads();
    if (threadIdx.x == 0) bsum[blockIdx.x] = ws[0] + ws[1] + ws[2] + ws[3];
}

// scan_write with inlined block-offset scan.
__global__ __launch_bounds__(256) void scan_write(
    const int* __restrict__ cnt, const int* __restrict__ bsum, int nb,
    int* __restrict__ rowptr, int n) {
    __shared__ int s_boff, s_total;
    int lane = threadIdx.x & 63, wid = threadIdx.x >> 6;
    if (threadIdx.x < 64) {
        int carry = 0;
        for (int base = 0; base < nb; base += 64) {
            int i = base + lane;
            int v = (i < nb) ? bsum[i] : 0;
            int orig = v;
            #pragma unroll
            for (int off = 1; off < 64; off <<= 1) {
                int t = __shfl_up(v, off, 64);
                if (lane >= off) v += t;
            }
            if (i == (int)blockIdx.x) s_boff = carry + v - orig;  // exclusive
            carry += __shfl(v, 63, 64);
        }
        if (lane == 0) s_total = carry;
    }
    int base = blockIdx.x * 1024 + threadIdx.x * 4;
    int4 v = make_int4(0, 0, 0, 0);
    if (base + 3 < n) {
        v = *(const int4*)(cnt + base);
    } else {
        if (base + 0 < n) v.x = cnt[base + 0];
        if (base + 1 < n) v.y = cnt[base + 1];
        if (base + 2 < n) v.z = cnt[base + 2];
        if (base + 3 < n) v.w = cnt[base + 3];
    }
    int t0 = v.x, t1 = t0 + v.y, t2 = t1 + v.z, t3 = t2 + v.w;  // inclusive
    int sc = t3;
    #pragma unroll
    for (int off = 1; off < 64; off <<= 1) {
        int t = __shfl_up(sc, off, 64);
        if (lane >= off) sc += t;
    }
    __shared__ int ws[4];
    if (lane == 63) ws[wid] = sc;
    __syncthreads();
    int woff = 0;
    for (int w = 0; w < wid; ++w) woff += ws[w];
    int off0 = s_boff + woff + sc - t3;  // exclusive at base
    if (base + 3 < n) {
        *(int4*)(rowptr + base) = make_int4(off0, off0 + t0, off0 + t1, off0 + t2);
    } else {
        if (base + 0 < n) rowptr[base + 0] = off0;
        if (base + 1 < n) rowptr[base + 1] = off0 + t0;
        if (base + 2 < n) rowptr[base + 2] = off0 + t1;
        if (base + 3 < n) rowptr[base + 3] = off0 + t2;
    }
    if (blockIdx.x == 0 && threadIdx.x == 0) rowptr[n] = s_total;
}

// Atomic-free scatter, 4 edges/thread: slot = rowptr[d] + epos[e].
__global__ void scatter_edges(const int* __restrict__ src, const int* __restrict__ dst,
                              const int* __restrict__ epos,
                              const float* __restrict__ dinv, const int* __restrict__ rowptr,
                              unsigned* __restrict__ cwp, int E) {
    int e = (blockIdx.x * blockDim.x + threadIdx.x) * 4;
    if (e + 3 < E) {
        i4v s4 = __builtin_nontemporal_load((const i4v*)(src + e));
        i4v d4 = __builtin_nontemporal_load((const i4v*)(dst + e));
        i4v p4 = __builtin_nontemporal_load((const i4v*)(epos + e));
        int i0 = rowptr[d4.x] + p4.x;
        int i1 = rowptr[d4.y] + p4.y;
        int i2 = rowptr[d4.z] + p4.z;
        int i3 = rowptr[d4.w] + p4.w;
        float dd0 = dinv[d4.x], dd1 = dinv[d4.y], dd2 = dinv[d4.z], dd3 = dinv[d4.w];
        unsigned pk0 = (unsigned)(unsigned short)s4.x | ((unsigned)f2h(dinv[s4.x] * dd0) << 16);
        unsigned pk1 = (unsigned)(unsigned short)s4.y | ((unsigned)f2h(dinv[s4.y] * dd1) << 16);
        unsigned pk2 = (unsigned)(unsigned short)s4.z | ((unsigned)f2h(dinv[s4.z] * dd2) << 16);
        unsigned pk3 = (unsigned)(unsigned short)s4.w | ((unsigned)f2h(dinv[s4.w] * dd3) << 16);
        __builtin_nontemporal_store(pk0, cwp + i0);
        __builtin_nontemporal_store(pk1, cwp + i1);
        __builtin_nontemporal_store(pk2, cwp + i2);
        __builtin_nontemporal_store(pk3, cwp + i3);
    } else {
        for (int k = 0; k < 4; ++k)
            if (e + k < E) {
                int s = src[e + k], d = dst[e + k];
                int idx = rowptr[d] + epos[e + k];
                float w = dinv[s] * dinv[d];
                cwp[idx] = (unsigned)(unsigned short)s | ((unsigned)f2h(w) << 16);
            }
    }
}

// One 32-lane group per node. Lanes 0..23 aggregate A_hat x1 (24 ch);
// gathers from padded [N][32] bf16 rows. One-rcp fused gates.
__global__ __launch_bounds__(256) void agg1_layer1(
    const float* __restrict__ X, const unsigned short* __restrict__ Xh,
    const int* __restrict__ rowptr, const unsigned* __restrict__ cwp,
    const float* __restrict__ dinv, const float* __restrict__ small,
    unsigned short* __restrict__ hout, unsigned short* __restrict__ atimeh, int n) {
    int lane = threadIdx.x & 31;
    int node = (blockIdx.x * blockDim.x + threadIdx.x) >> 5;
    if (node >= n) return;
    int beg = rowptr[node], end = rowptr[node + 1];
    float acc = 0.f;
    if (lane < 24) {
        float dn = dinv[node];
        acc = dn * dn * __builtin_nontemporal_load(X + (size_t)node * 24 + lane);
        float a0 = 0.f, a1 = 0.f, a2 = 0.f, a3 = 0.f;
        int j = beg;
        for (; j + 4 <= end; j += 4) {
            unsigned c0 = __builtin_nontemporal_load(cwp + j);
            unsigned c1 = __builtin_nontemporal_load(cwp + j + 1);
            unsigned c2 = __builtin_nontemporal_load(cwp + j + 2);
            unsigned c3 = __builtin_nontemporal_load(cwp + j + 3);
            a0 = fmaf(h2f(c0 >> 16), bf2f(Xh[(c0 & 0xFFFFu) * 32 + lane]), a0);
            a1 = fmaf(h2f(c1 >> 16), bf2f(Xh[(c1 & 0xFFFFu) * 32 + lane]), a1);
            a2 = fmaf(h2f(c2 >> 16), bf2f(Xh[(c2 & 0xFFFFu) * 32 + lane]), a2);
            a3 = fmaf(h2f(c3 >> 16), bf2f(Xh[(c3 & 0xFFFFu) * 32 + lane]), a3);
        }
        for (; j < end; ++j) {
            unsigned c = __builtin_nontemporal_load(cwp + j);
            acc = fmaf(h2f(c >> 16), bf2f(Xh[(c & 0xFFFFu) * 32 + lane]), acc);
        }
        acc += (a0 + a1) + (a2 + a3);
    }
    if (lane >= 12 && lane < 24)
        atimeh[(size_t)node * 12 + lane - 12] = f2bf(acc);
    float a0z = small[lane], a1z = small[32 + lane], c1z = small[64 + lane];
    float a0h = small[96 + lane], a1h = small[128 + lane], c1h = small[160 + lane];
    float hs = 0.f;
    #pragma unroll
    for (int p = 0; p < 12; ++p) {
        float x0 = __shfl(acc, p, 32);
        float x1 = __shfl(acc, 12 + p, 32);
        float ez = __expf(-fmaf(x0, a0z, fmaf(x1, a1z, c1z)));
        float eh = __expf(-2.f * fmaf(x0, a0h, fmaf(x1, a1h, c1h)));
        float R = __builtin_amdgcn_rcpf((1.f + ez) * (1.f + eh));
        hs = fmaf(small[192 + p] * ez * (1.f - eh), R, hs);
    }
    hout[(size_t)node * 32 + lane] = f2bf(fmaxf(hs, 0.f));
}

// Fused agg2 + layer2 + final MLP. One 64-lane wave per node; 8 waves/block.
// Gather: 4 edge-groups x 16 lanes, u32 loads = 2 bf16 channels per lane.
__global__ __launch_bounds__(512, 8) void agg2_layer2(
    const unsigned short* __restrict__ hbuf, const unsigned short* __restrict__ atimeh,
    const int* __restrict__ rowptr, const unsigned* __restrict__ cwp,
    const float* __restrict__ dinv, const float* __restrict__ small,
    const float* __restrict__ lw1, const float* __restrict__ lb1,
    const float* __restrict__ lw2, const float* __restrict__ lb2,
    float* __restrict__ out, int n) {
    __shared__ __align__(16) float4 wqs[1024];          // 16 KB M2z/M2h interleaved
    __shared__ __align__(16) float s_lw1[2048];          // 8 KB [j][k] 64x32
    __shared__ float s_pr[16];
    __shared__ __align__(16) float4 scr[8][16];          // per-wave av/h2 scratch

    for (int t = threadIdx.x; t < 4096; t += 512) {
        int s = t & 3, j = (t >> 2) & 63, k2 = t >> 8;
        int k = 2 * k2 + (s >> 1), zh = s & 1;
        ((float*)wqs)[t] = small[256 + zh * 2048 + k * 64 + j];
    }
    for (int t = threadIdx.x; t < 2048; t += 512) s_lw1[t] = lw1[t];
    if (threadIdx.x < 16) s_pr[threadIdx.x] = (threadIdx.x < 12) ? small[4608 + threadIdx.x] : 0.f;
    __syncthreads();

    int lane = threadIdx.x & 63;
    int wid = threadIdx.x >> 6;
    int ch = lane & 31, half = lane >> 5;
    int eg = lane >> 4;          // edge group 0..3
    int k16 = lane & 15;         // channel pair index
    const unsigned* hbuf32 = (const unsigned*)hbuf;   // [N][16] u32 view
    float qz = small[4352 + lane], qh = small[4416 + lane];
    float czv = small[4480 + lane], chv = small[4544 + lane];
    float lb1v = lb1[ch];
    int p_ = lane & 15, q_ = lane >> 4;
    float lb2v = (q_ == 0 && p_ < 12) ? lb2[p_] : 0.f;
    float wlw2[8];
    #pragma unroll
    for (int i = 0; i < 8; ++i)
        wlw2[i] = (p_ < 12) ? lw2[(q_ * 8 + i) * 12 + p_] : 0.f;

    int totalw = gridDim.x * 8;
    for (int node = blockIdx.x * 8 + wid; node < n; node += totalw) {
        // early-issue the independent atime row (hides under gather)
        const u2v* trow = (const u2v*)(atimeh + (size_t)node * 12);
        u2v tA = __builtin_nontemporal_load(trow);
        u2v tB = __builtin_nontemporal_load(trow + 1);
        u2v tC = __builtin_nontemporal_load(trow + 2);

        // ---- fused agg2: 2 channels/lane, 4 edge groups ----
        int beg = rowptr[node], end = rowptr[node + 1];
        float dn = dinv[node];
        float accL = 0.f, accR = 0.f;
        if (eg == 0) {
            unsigned hv = hbuf32[(size_t)node * 16 + k16];
            float s = dn * dn;
            accL = s * bflo(hv);
            accR = s * bfhi(hv);
        }
        float aL1 = 0.f, aR1 = 0.f;
        int j = beg + eg;
        for (; j + 4 < end; j += 8) {
            unsigned ca = __builtin_nontemporal_load(cwp + j);
            unsigned cb = __builtin_nontemporal_load(cwp + j + 4);
            float wa = h2f(ca >> 16), wb = h2f(cb >> 16);
            unsigned ha = hbuf32[(size_t)(ca & 0xFFFFu) * 16 + k16];
            unsigned hb = hbuf32[(size_t)(cb & 0xFFFFu) * 16 + k16];
            accL = fmaf(wa, bflo(ha), accL); accR = fmaf(wa, bfhi(ha), accR);
            aL1  = fmaf(wb, bflo(hb), aL1);  aR1  = fmaf(wb, bfhi(hb), aR1);
        }
        if (j < end) {
            unsigned ca = __builtin_nontemporal_load(cwp + j);
            float wa = h2f(ca >> 16);
            unsigned ha = hbuf32[(size_t)(ca & 0xFFFFu) * 16 + k16];
            accL = fmaf(wa, bflo(ha), accL); accR = fmaf(wa, bfhi(ha), accR);
        }
        accL += aL1; accR += aR1;
        accL += __shfl_xor(accL, 16, 64);
        accL += __shfl_xor(accL, 32, 64);
        accR += __shfl_xor(accR, 16, 64);
        accR += __shfl_xor(accR, 32, 64);
        if (lane < 16) {
            float2 av2 = make_float2(accL, accR);
            ((float2*)&scr[wid][0])[k16] = av2;   // av[2k], av[2k+1]
        }
        asm volatile("s_waitcnt lgkmcnt(0)" ::: "memory");

        // ---- GEMV: p0z/p0h = av . M2z/M2h (col j=lane) ----
        float p0z = czv, p0h = chv;
        const float4* arow = &scr[wid][0];
        #pragma unroll
        for (int c = 0; c < 8; ++c) {
            float4 av = arow[c];
            float4 w0 = wqs[(2 * c) * 64 + lane];
            float4 w1 = wqs[(2 * c + 1) * 64 + lane];
            p0z = fmaf(av.x, w0.x, p0z); p0h = fmaf(av.x, w0.y, p0h);
            p0z = fmaf(av.y, w0.z, p0z); p0h = fmaf(av.y, w0.w, p0h);
            p0z = fmaf(av.z, w1.x, p0z); p0h = fmaf(av.z, w1.y, p0h);
            p0z = fmaf(av.w, w1.z, p0z); p0h = fmaf(av.w, w1.w, p0h);
        }
        float tt[12] = {bf2f((unsigned short)(tA.x & 0xFFFFu)), bf2f((unsigned short)(tA.x >> 16)),
                        bf2f((unsigned short)(tA.y & 0xFFFFu)), bf2f((unsigned short)(tA.y >> 16)),
                        bf2f((unsigned short)(tB.x & 0xFFFFu)), bf2f((unsigned short)(tB.x >> 16)),
                        bf2f((unsigned short)(tB.y & 0xFFFFu)), bf2f((unsigned short)(tB.y >> 16)),
                        bf2f((unsigned short)(tC.x & 0xFFFFu)), bf2f((unsigned short)(tC.x >> 16)),
                        bf2f((unsigned short)(tC.y & 0xFFFFu)), bf2f((unsigned short)(tC.y >> 16))};
        float acc2 = 0.f;
        #pragma unroll
        for (int p = 0; p < 12; ++p) {
            float t = tt[p];
            float ez = __expf(-fmaf(t, qz, p0z));
            float eh = __expf(-2.f * fmaf(t, qh, p0h));
            float R = __builtin_amdgcn_rcpf((1.f + ez) * (1.f + eh));
            acc2 = fmaf(s_pr[p] * ez * (1.f - eh), R, acc2);
        }
        float h2 = fmaxf(acc2, 0.f);
        ((float*)&scr[wid][0])[lane] = h2;
        asm volatile("s_waitcnt lgkmcnt(0)" ::: "memory");

        // ---- h3 = relu(h2 . lw1 + lb1), split over halves ----
        float h3 = half ? 0.f : lb1v;
        const float4* hrow = &scr[wid][half * 8];
        #pragma unroll
        for (int c = 0; c < 8; ++c) {
            float4 hv = hrow[c];
            int jb = half * 32 + c * 4;
            h3 = fmaf(hv.x, s_lw1[(jb + 0) * 32 + ch], h3);
            h3 = fmaf(hv.y, s_lw1[(jb + 1) * 32 + ch], h3);
            h3 = fmaf(hv.z, s_lw1[(jb + 2) * 32 + ch], h3);
            h3 = fmaf(hv.w, s_lw1[(jb + 3) * 32 + ch], h3);
        }
        h3 += __shfl_xor(h3, 32, 64);
        h3 = fmaxf(h3, 0.f);

        // ---- out = h3 . lw2 + lb2 (lw2 in registers) ----
        float o = lb2v;
        #pragma unroll
        for (int i = 0; i < 8; ++i) {
            float h3k = __shfl(h3, q_ * 8 + i, 64);
            o = fmaf(h3k, wlw2[i], o);
        }
        o += __shfl_xor(o, 16, 64);
        o += __shfl_xor(o, 32, 64);
        if (lane < 12)
            __builtin_nontemporal_store(o, out + (size_t)node * 12 + lane);
    }
}

extern "C" void kernel_launch(void* const* d_in, const int* in_sizes, int n_in,
                              void* d_out, int out_size, void* d_ws, size_t ws_size,
                              hipStream_t stream) {
    const float* x1   = (const float*)d_in[0];
    const int*   eidx = (const int*)d_in[1];
    const float* W1   = (const float*)d_in[4];
    const float* b1   = (const float*)d_in[5];
    const float* Wl1  = (const float*)d_in[6];
    const float* bl1  = (const float*)d_in[7];
    const float* att1 = (const float*)d_in[8];
    const float* W2   = (const float*)d_in[9];
    const float* b2   = (const float*)d_in[10];
    const float* Wl2  = (const float*)d_in[11];
    const float* bl2  = (const float*)d_in[12];
    const float* att2 = (const float*)d_in[13];
    const float* lw1  = (const float*)d_in[14];
    const float* lb1  = (const float*)d_in[15];
    const float* lw2  = (const float*)d_in[16];
    const float* lb2  = (const float*)d_in[17];
    (void)n_in; (void)out_size; (void)ws_size;

    int N = in_sizes[0] / 24;
    int E = in_sizes[1] / 2;
    const int* srcp = eidx;
    const int* dstp = eidx + E;
    int nb = (N + 1023) / 1024;
    int n32 = N * 32;
    int ncb = (n32 / 4 + 255) / 256;        // cvt blocks
    int neb4 = ((E + 3) / 4 + 255) / 256;   // count/scatter blocks (4 edges/thread)

    char* ws = (char*)d_ws;
    size_t off = 0;
    auto alloc = [&](size_t bytes) -> char* {
        char* p = ws + off;
        off += (bytes + 511) & ~(size_t)511;
        return p;
    };
    int*            cnt    = (int*)alloc((size_t)N * 4);
    int*            rowptr = (int*)alloc((size_t)(N + 1) * 4);
    float*          dinv   = (float*)alloc((size_t)N * 4);
    int*            epos   = (int*)alloc((size_t)E * 4);
    unsigned*       cwp    = (unsigned*)alloc((size_t)E * 4);
    unsigned short* x1h    = (unsigned short*)alloc((size_t)n32 * 2);
    unsigned short* hbuf   = (unsigned short*)alloc((size_t)N * 32 * 2);
    unsigned short* atimeh = (unsigned short*)alloc((size_t)N * 12 * 2);
    float*          small  = (float*)alloc(4624 * 4);
    int*            bsum   = (int*)alloc((size_t)nb * 4);

    (void)hipMemsetAsync(cnt, 0, (size_t)N * 4, stream);
    prep_cvt_count<<<PREPB + ncb + neb4, 256, 0, stream>>>(
        x1, x1h, n32, ncb, dstp, cnt, epos, E,
        W1, b1, Wl1, bl1, att1, W2, b2, Wl2, bl2, att2, small);
    scan_blocksum<<<nb, 256, 0, stream>>>(cnt, dinv, bsum, N);
    scan_write<<<nb, 256, 0, stream>>>(cnt, bsum, nb, rowptr, N);
    scatter_edges<<<neb4, 256, 0, stream>>>(srcp, dstp, epos, dinv, rowptr, cwp, E);
    agg1_layer1<<<(N * 32 + 255) / 256, 256, 0, stream>>>(x1, x1h, rowptr, cwp, dinv, small, hbuf, atimeh, N);
    agg2_layer2<<<1024, 512, 0, stream>>>(hbuf, atimeh, rowptr, cwp, dinv, small,
                                          lw1, lb1, lw2, lb2, (float*)d_out, N);
}

// Round 22
// 146.894 us; speedup vs baseline: 3.5880x; 1.0104x over previous
//
#include <hip/hip_runtime.h>
#include <hip/hip_bf16.h>
#include <hip/hip_fp16.h>
#include <math.h>

// ---------------------------------------------------------------------------
// A3T-GCN two-layer, restructured (see round-1 notes):
//   - H == 0 => R gate dead, cell = (1-Z)*tanh(...)
//   - A_hat commutes with W => one propagation per layer, folded gate matrices
//   - layer2 time channel reuses layer-1 propagation (rank-1 per period)
// Round 22: agg1 gather remapped like agg2's r21 change - 2 edge-groups x
// 16 lanes, lane k<12 loads u32 = 2 bf16 channels (12 loads/edge vs 24).
// Gate phase reads channel p via compile-time shfl select; atime stored as
// u32 pairs. Rest identical to round 21 (148.4 us).
// ---------------------------------------------------------------------------

typedef float f4v __attribute__((ext_vector_type(4)));
typedef unsigned u2v __attribute__((ext_vector_type(2)));
typedef int i4v __attribute__((ext_vector_type(4)));

#define PREPB 17  // prep block range at the head of prep_cvt_count

static __device__ __forceinline__ unsigned short f2bf(float f) {
    unsigned u = __float_as_uint(f);
    unsigned r = (u + 0x7FFFu + ((u >> 16) & 1u)) >> 16;  // RNE
    return (unsigned short)r;
}
static __device__ __forceinline__ float bf2f(unsigned short u) {
    return __uint_as_float(((unsigned)u) << 16);
}
static __device__ __forceinline__ float bflo(unsigned v) {
    return __uint_as_float(v << 16);
}
static __device__ __forceinline__ float bfhi(unsigned v) {
    return __uint_as_float(v & 0xFFFF0000u);
}
static __device__ __forceinline__ unsigned short f2h(float f) {
    __half h = __float2half_rn(f);
    return *reinterpret_cast<unsigned short*>(&h);
}
static __device__ __forceinline__ float h2f(unsigned short u) {
    __half h;
    *reinterpret_cast<unsigned short*>(&h) = u;
    return __half2float(h);
}

// small[] layout (floats):
//   [0:32)a0z [32:64)a1z [64:96)c1z [96:128)a0h [128:160)a1h [160:192)c1h [192:204)probs1
//   [256:2304) M2z   [2304:4352) M2h
//   [4352:4416) q2z [4416:4480) q2h [4480:4544) c2z [4544:4608) c2h [4608:4620) probs2
__global__ void prep_cvt_count(
    const float* __restrict__ in, unsigned short* __restrict__ outh,
    int n32, int ncb,
    const int* __restrict__ dst, int* __restrict__ cnt,
    int* __restrict__ epos, int E,
    const float* __restrict__ W1, const float* __restrict__ b1,
    const float* __restrict__ Wl1, const float* __restrict__ bl1,
    const float* __restrict__ att1,
    const float* __restrict__ W2, const float* __restrict__ b2,
    const float* __restrict__ Wl2, const float* __restrict__ bl2,
    const float* __restrict__ att2, float* __restrict__ small) {
    int tid = threadIdx.x;
    if ((int)blockIdx.x < PREPB) {
        if (blockIdx.x == 0) {
            if (tid < 192) {  // layer-1 folds
                int which = tid >> 5, hh = tid & 31;
                int g = (which < 3) ? 0 : 2;
                int kind = which % 3;  // 0:a0 1:a1 2:c
                const float* Wl = Wl1 + g * 64 * 32;
                float s = 0.f;
                if (kind < 2) {
                    const float* Wr = W1 + g * 2 * 32 + kind * 32;
                    for (int k = 0; k < 32; ++k) s += Wr[k] * Wl[k * 32 + hh];
                } else {
                    const float* br = b1 + g * 32;
                    for (int k = 0; k < 32; ++k) s += br[k] * Wl[k * 32 + hh];
                    s += bl1[g * 32 + hh];
                }
                small[tid] = s;
            }
            {  // q (time row) and c (bias) folds: 256 outputs
                int which = tid >> 6, j = tid & 63;
                int g = (which == 0 || which == 2) ? 0 : 2;
                const float* Wl = Wl2 + g * 128 * 64;
                float s = 0.f;
                if (which < 2) {
                    const float* Wr = W2 + g * 33 * 64 + 32 * 64;
                    for (int k = 0; k < 64; ++k) s += Wr[k] * Wl[k * 64 + j];
                } else {
                    const float* br = b2 + g * 64;
                    for (int k = 0; k < 64; ++k) s += br[k] * Wl[k * 64 + j];
                    s += bl2[g * 64 + j];
                }
                small[4352 + tid] = s;
            }
            if (tid == 0) {  // softmax(att1)
                float mx = att1[0];
                for (int p = 1; p < 12; ++p) mx = fmaxf(mx, att1[p]);
                float e[12], sm = 0.f;
                for (int p = 0; p < 12; ++p) { e[p] = expf(att1[p] - mx); sm += e[p]; }
                for (int p = 0; p < 12; ++p) small[192 + p] = e[p] / sm;
            } else if (tid == 1) {  // softmax(att2)
                float mx = att2[0];
                for (int p = 1; p < 12; ++p) mx = fmaxf(mx, att2[p]);
                float e[12], sm = 0.f;
                for (int p = 0; p < 12; ++p) { e[p] = expf(att2[p] - mx); sm += e[p]; }
                for (int p = 0; p < 12; ++p) small[4608 + p] = e[p] / sm;
            }
        } else {  // blocks 1..16: M2 fold, t in [0,4096)
            int t = (blockIdx.x - 1) * 256 + tid;
            int gg = t >> 11;
            int rem = t & 2047;
            int i = rem >> 6, j = rem & 63;
            int g = gg ? 2 : 0;
            const float* Wl = Wl2 + g * 128 * 64;
            const float* Wr = W2 + g * 33 * 64 + i * 64;
            float s = 0.f;
            for (int k = 0; k < 64; ++k) s += Wr[k] * Wl[k * 64 + j];
            small[256 + gg * 2048 + i * 64 + j] = s;
        }
    } else if ((int)blockIdx.x < PREPB + ncb) {
        int i = ((blockIdx.x - PREPB) * blockDim.x + tid) * 4;
        if (i < n32) {
            int node = i >> 5, c = i & 31;
            const float* row = in + (size_t)node * 24;
            ushort4 u;
            u.x = (c + 0 < 24) ? f2bf(__builtin_nontemporal_load(row + c + 0)) : (unsigned short)0;
            u.y = (c + 1 < 24) ? f2bf(__builtin_nontemporal_load(row + c + 1)) : (unsigned short)0;
            u.z = (c + 2 < 24) ? f2bf(__builtin_nontemporal_load(row + c + 2)) : (unsigned short)0;
            u.w = (c + 3 < 24) ? f2bf(__builtin_nontemporal_load(row + c + 3)) : (unsigned short)0;
            *(ushort4*)(outh + i) = u;
        }
    } else {
        int e = (((int)blockIdx.x - PREPB - ncb) * blockDim.x + tid) * 4;
        if (e + 3 < E) {
            i4v d4 = __builtin_nontemporal_load((const i4v*)(dst + e));
            i4v p4;
            p4.x = atomicAdd(&cnt[d4.x], 1);
            p4.y = atomicAdd(&cnt[d4.y], 1);
            p4.z = atomicAdd(&cnt[d4.z], 1);
            p4.w = atomicAdd(&cnt[d4.w], 1);
            __builtin_nontemporal_store(p4, (i4v*)(epos + e));
        } else {
            for (int k = 0; k < 4; ++k)
                if (e + k < E) {
                    int d = dst[e + k];
                    epos[e + k] = atomicAdd(&cnt[d], 1);
                }
        }
    }
}

// --- parallel exclusive scan of cnt -> rowptr, plus dinv ------------------
__global__ __launch_bounds__(256) void scan_blocksum(
    const int* __restrict__ cnt, float* __restrict__ dinv,
    int* __restrict__ bsum, int n) {
    int base = blockIdx.x * 1024 + threadIdx.x * 4;
    int s = 0;
    if (base + 3 < n) {
        int4 v = *(const int4*)(cnt + base);
        dinv[base + 0] = rsqrtf((float)v.x + 1.f);
        dinv[base + 1] = rsqrtf((float)v.y + 1.f);
        dinv[base + 2] = rsqrtf((float)v.z + 1.f);
        dinv[base + 3] = rsqrtf((float)v.w + 1.f);
        s = v.x + v.y + v.z + v.w;
    } else {
        for (int k = 0; k < 4; ++k)
            if (base + k < n) {
                int v = cnt[base + k];
                dinv[base + k] = rsqrtf((float)v + 1.f);
                s += v;
            }
    }
    #pragma unroll
    for (int off = 32; off > 0; off >>= 1) s += __shfl_down(s, off, 64);
    __shared__ int ws[4];
    int lane = threadIdx.x & 63, wid = threadIdx.x >> 6;
    if (lane == 0) ws[wid] = s;
    __syncthreads();
    if (threadIdx.x == 0) bsum[blockIdx.x] = ws[0] + ws[1] + ws[2] + ws[3];
}

// scan_write with inlined block-offset scan.
__global__ __launch_bounds__(256) void scan_write(
    const int* __restrict__ cnt, const int* __restrict__ bsum, int nb,
    int* __restrict__ rowptr, int n) {
    __shared__ int s_boff, s_total;
    int lane = threadIdx.x & 63, wid = threadIdx.x >> 6;
    if (threadIdx.x < 64) {
        int carry = 0;
        for (int base = 0; base < nb; base += 64) {
            int i = base + lane;
            int v = (i < nb) ? bsum[i] : 0;
            int orig = v;
            #pragma unroll
            for (int off = 1; off < 64; off <<= 1) {
                int t = __shfl_up(v, off, 64);
                if (lane >= off) v += t;
            }
            if (i == (int)blockIdx.x) s_boff = carry + v - orig;  // exclusive
            carry += __shfl(v, 63, 64);
        }
        if (lane == 0) s_total = carry;
    }
    int base = blockIdx.x * 1024 + threadIdx.x * 4;
    int4 v = make_int4(0, 0, 0, 0);
    if (base + 3 < n) {
        v = *(const int4*)(cnt + base);
    } else {
        if (base + 0 < n) v.x = cnt[base + 0];
        if (base + 1 < n) v.y = cnt[base + 1];
        if (base + 2 < n) v.z = cnt[base + 2];
        if (base + 3 < n) v.w = cnt[base + 3];
    }
    int t0 = v.x, t1 = t0 + v.y, t2 = t1 + v.z, t3 = t2 + v.w;  // inclusive
    int sc = t3;
    #pragma unroll
    for (int off = 1; off < 64; off <<= 1) {
        int t = __shfl_up(sc, off, 64);
        if (lane >= off) sc += t;
    }
    __shared__ int ws[4];
    if (lane == 63) ws[wid] = sc;
    __syncthreads();
    int woff = 0;
    for (int w = 0; w < wid; ++w) woff += ws[w];
    int off0 = s_boff + woff + sc - t3;  // exclusive at base
    if (base + 3 < n) {
        *(int4*)(rowptr + base) = make_int4(off0, off0 + t0, off0 + t1, off0 + t2);
    } else {
        if (base + 0 < n) rowptr[base + 0] = off0;
        if (base + 1 < n) rowptr[base + 1] = off0 + t0;
        if (base + 2 < n) rowptr[base + 2] = off0 + t1;
        if (base + 3 < n) rowptr[base + 3] = off0 + t2;
    }
    if (blockIdx.x == 0 && threadIdx.x == 0) rowptr[n] = s_total;
}

// Atomic-free scatter, 4 edges/thread: slot = rowptr[d] + epos[e].
__global__ void scatter_edges(const int* __restrict__ src, const int* __restrict__ dst,
                              const int* __restrict__ epos,
                              const float* __restrict__ dinv, const int* __restrict__ rowptr,
                              unsigned* __restrict__ cwp, int E) {
    int e = (blockIdx.x * blockDim.x + threadIdx.x) * 4;
    if (e + 3 < E) {
        i4v s4 = __builtin_nontemporal_load((const i4v*)(src + e));
        i4v d4 = __builtin_nontemporal_load((const i4v*)(dst + e));
        i4v p4 = __builtin_nontemporal_load((const i4v*)(epos + e));
        int i0 = rowptr[d4.x] + p4.x;
        int i1 = rowptr[d4.y] + p4.y;
        int i2 = rowptr[d4.z] + p4.z;
        int i3 = rowptr[d4.w] + p4.w;
        float dd0 = dinv[d4.x], dd1 = dinv[d4.y], dd2 = dinv[d4.z], dd3 = dinv[d4.w];
        unsigned pk0 = (unsigned)(unsigned short)s4.x | ((unsigned)f2h(dinv[s4.x] * dd0) << 16);
        unsigned pk1 = (unsigned)(unsigned short)s4.y | ((unsigned)f2h(dinv[s4.y] * dd1) << 16);
        unsigned pk2 = (unsigned)(unsigned short)s4.z | ((unsigned)f2h(dinv[s4.z] * dd2) << 16);
        unsigned pk3 = (unsigned)(unsigned short)s4.w | ((unsigned)f2h(dinv[s4.w] * dd3) << 16);
        __builtin_nontemporal_store(pk0, cwp + i0);
        __builtin_nontemporal_store(pk1, cwp + i1);
        __builtin_nontemporal_store(pk2, cwp + i2);
        __builtin_nontemporal_store(pk3, cwp + i3);
    } else {
        for (int k = 0; k < 4; ++k)
            if (e + k < E) {
                int s = src[e + k], d = dst[e + k];
                int idx = rowptr[d] + epos[e + k];
                float w = dinv[s] * dinv[d];
                cwp[idx] = (unsigned)(unsigned short)s | ((unsigned)f2h(w) << 16);
            }
    }
}

// One 32-lane group per node. Gather: 2 edge-groups x 16 lanes, lane k<12
// loads u32 = 2 bf16 channels (ch 2k, 2k+1 of the 24 input channels).
// Combine shfl_xor(16,32); gates read channel p via compile-time shfl
// select. atime stored as u32 pairs. One-rcp fused gates.
__global__ __launch_bounds__(256) void agg1_layer1(
    const float* __restrict__ X, const unsigned short* __restrict__ Xh,
    const int* __restrict__ rowptr, const unsigned* __restrict__ cwp,
    const float* __restrict__ dinv, const float* __restrict__ small,
    unsigned short* __restrict__ hout, unsigned short* __restrict__ atimeh, int n) {
    int lane = threadIdx.x & 31;
    int node = (blockIdx.x * blockDim.x + threadIdx.x) >> 5;
    if (node >= n) return;
    int eg = lane >> 4;          // edge group 0/1
    int k16 = lane & 15;         // channel-pair index
    const unsigned* Xh32 = (const unsigned*)Xh;   // [N][16] u32 view
    int beg = rowptr[node], end = rowptr[node + 1];
    float accL = 0.f, accR = 0.f;
    if (k16 < 12) {
        if (eg == 0) {
            float s = dinv[node];
            s *= s;
            accL = s * __builtin_nontemporal_load(X + (size_t)node * 24 + 2 * k16);
            accR = s * __builtin_nontemporal_load(X + (size_t)node * 24 + 2 * k16 + 1);
        }
        float aL1 = 0.f, aR1 = 0.f;
        int j = beg + eg;
        for (; j + 2 < end; j += 4) {
            unsigned ca = __builtin_nontemporal_load(cwp + j);
            unsigned cb = __builtin_nontemporal_load(cwp + j + 2);
            float wa = h2f(ca >> 16), wb = h2f(cb >> 16);
            unsigned ha = Xh32[(size_t)(ca & 0xFFFFu) * 16 + k16];
            unsigned hb = Xh32[(size_t)(cb & 0xFFFFu) * 16 + k16];
            accL = fmaf(wa, bflo(ha), accL); accR = fmaf(wa, bfhi(ha), accR);
            aL1  = fmaf(wb, bflo(hb), aL1);  aR1  = fmaf(wb, bfhi(hb), aR1);
        }
        if (j < end) {
            unsigned ca = __builtin_nontemporal_load(cwp + j);
            float wa = h2f(ca >> 16);
            unsigned ha = Xh32[(size_t)(ca & 0xFFFFu) * 16 + k16];
            accL = fmaf(wa, bflo(ha), accL); accR = fmaf(wa, bfhi(ha), accR);
        }
        accL += aL1; accR += aR1;
    }
    accL += __shfl_xor(accL, 16, 32);
    accR += __shfl_xor(accR, 16, 32);
    // atime = channels 12..23 = pairs k16 6..11; write u32 pairs
    if (lane >= 6 && lane < 12) {
        unsigned pk = ((unsigned)f2bf(accL)) | (((unsigned)f2bf(accR)) << 16);
        __builtin_nontemporal_store(pk, (unsigned*)atimeh + (size_t)node * 6 + (lane - 6));
    }
    float a0z = small[lane], a1z = small[32 + lane], c1z = small[64 + lane];
    float a0h = small[96 + lane], a1h = small[128 + lane], c1h = small[160 + lane];
    float hs = 0.f;
    #pragma unroll
    for (int p = 0; p < 12; ++p) {
        float x0 = __shfl((p & 1) ? accR : accL, p >> 1, 32);
        float x1 = __shfl((p & 1) ? accR : accL, 6 + (p >> 1), 32);
        float ez = __expf(-fmaf(x0, a0z, fmaf(x1, a1z, c1z)));
        float eh = __expf(-2.f * fmaf(x0, a0h, fmaf(x1, a1h, c1h)));
        float R = __builtin_amdgcn_rcpf((1.f + ez) * (1.f + eh));
        hs = fmaf(small[192 + p] * ez * (1.f - eh), R, hs);
    }
    hout[(size_t)node * 32 + lane] = f2bf(fmaxf(hs, 0.f));
}

// Fused agg2 + layer2 + final MLP. One 64-lane wave per node; 8 waves/block.
// Gather: 4 edge-groups x 16 lanes, u32 loads = 2 bf16 channels per lane.
__global__ __launch_bounds__(512, 8) void agg2_layer2(
    const unsigned short* __restrict__ hbuf, const unsigned short* __restrict__ atimeh,
    const int* __restrict__ rowptr, const unsigned* __restrict__ cwp,
    const float* __restrict__ dinv, const float* __restrict__ small,
    const float* __restrict__ lw1, const float* __restrict__ lb1,
    const float* __restrict__ lw2, const float* __restrict__ lb2,
    float* __restrict__ out, int n) {
    __shared__ __align__(16) float4 wqs[1024];          // 16 KB M2z/M2h interleaved
    __shared__ __align__(16) float s_lw1[2048];          // 8 KB [j][k] 64x32
    __shared__ float s_pr[16];
    __shared__ __align__(16) float4 scr[8][16];          // per-wave av/h2 scratch

    for (int t = threadIdx.x; t < 4096; t += 512) {
        int s = t & 3, j = (t >> 2) & 63, k2 = t >> 8;
        int k = 2 * k2 + (s >> 1), zh = s & 1;
        ((float*)wqs)[t] = small[256 + zh * 2048 + k * 64 + j];
    }
    for (int t = threadIdx.x; t < 2048; t += 512) s_lw1[t] = lw1[t];
    if (threadIdx.x < 16) s_pr[threadIdx.x] = (threadIdx.x < 12) ? small[4608 + threadIdx.x] : 0.f;
    __syncthreads();

    int lane = threadIdx.x & 63;
    int wid = threadIdx.x >> 6;
    int ch = lane & 31, half = lane >> 5;
    int eg = lane >> 4;          // edge group 0..3
    int k16 = lane & 15;         // channel pair index
    const unsigned* hbuf32 = (const unsigned*)hbuf;   // [N][16] u32 view
    float qz = small[4352 + lane], qh = small[4416 + lane];
    float czv = small[4480 + lane], chv = small[4544 + lane];
    float lb1v = lb1[ch];
    int p_ = lane & 15, q_ = lane >> 4;
    float lb2v = (q_ == 0 && p_ < 12) ? lb2[p_] : 0.f;
    float wlw2[8];
    #pragma unroll
    for (int i = 0; i < 8; ++i)
        wlw2[i] = (p_ < 12) ? lw2[(q_ * 8 + i) * 12 + p_] : 0.f;

    int totalw = gridDim.x * 8;
    for (int node = blockIdx.x * 8 + wid; node < n; node += totalw) {
        // early-issue the independent atime row (hides under gather)
        const u2v* trow = (const u2v*)(atimeh + (size_t)node * 12);
        u2v tA = __builtin_nontemporal_load(trow);
        u2v tB = __builtin_nontemporal_load(trow + 1);
        u2v tC = __builtin_nontemporal_load(trow + 2);

        // ---- fused agg2: 2 channels/lane, 4 edge groups ----
        int beg = rowptr[node], end = rowptr[node + 1];
        float dn = dinv[node];
        float accL = 0.f, accR = 0.f;
        if (eg == 0) {
            unsigned hv = hbuf32[(size_t)node * 16 + k16];
            float s = dn * dn;
            accL = s * bflo(hv);
            accR = s * bfhi(hv);
        }
        float aL1 = 0.f, aR1 = 0.f;
        int j = beg + eg;
        for (; j + 4 < end; j += 8) {
            unsigned ca = __builtin_nontemporal_load(cwp + j);
            unsigned cb = __builtin_nontemporal_load(cwp + j + 4);
            float wa = h2f(ca >> 16), wb = h2f(cb >> 16);
            unsigned ha = hbuf32[(size_t)(ca & 0xFFFFu) * 16 + k16];
            unsigned hb = hbuf32[(size_t)(cb & 0xFFFFu) * 16 + k16];
            accL = fmaf(wa, bflo(ha), accL); accR = fmaf(wa, bfhi(ha), accR);
            aL1  = fmaf(wb, bflo(hb), aL1);  aR1  = fmaf(wb, bfhi(hb), aR1);
        }
        if (j < end) {
            unsigned ca = __builtin_nontemporal_load(cwp + j);
            float wa = h2f(ca >> 16);
            unsigned ha = hbuf32[(size_t)(ca & 0xFFFFu) * 16 + k16];
            accL = fmaf(wa, bflo(ha), accL); accR = fmaf(wa, bfhi(ha), accR);
        }
        accL += aL1; accR += aR1;
        accL += __shfl_xor(accL, 16, 64);
        accL += __shfl_xor(accL, 32, 64);
        accR += __shfl_xor(accR, 16, 64);
        accR += __shfl_xor(accR, 32, 64);
        if (lane < 16) {
            float2 av2 = make_float2(accL, accR);
            ((float2*)&scr[wid][0])[k16] = av2;   // av[2k], av[2k+1]
        }
        asm volatile("s_waitcnt lgkmcnt(0)" ::: "memory");

        // ---- GEMV: p0z/p0h = av . M2z/M2h (col j=lane) ----
        float p0z = czv, p0h = chv;
        const float4* arow = &scr[wid][0];
        #pragma unroll
        for (int c = 0; c < 8; ++c) {
            float4 av = arow[c];
            float4 w0 = wqs[(2 * c) * 64 + lane];
            float4 w1 = wqs[(2 * c + 1) * 64 + lane];
            p0z = fmaf(av.x, w0.x, p0z); p0h = fmaf(av.x, w0.y, p0h);
            p0z = fmaf(av.y, w0.z, p0z); p0h = fmaf(av.y, w0.w, p0h);
            p0z = fmaf(av.z, w1.x, p0z); p0h = fmaf(av.z, w1.y, p0h);
            p0z = fmaf(av.w, w1.z, p0z); p0h = fmaf(av.w, w1.w, p0h);
        }
        float tt[12] = {bf2f((unsigned short)(tA.x & 0xFFFFu)), bf2f((unsigned short)(tA.x >> 16)),
                        bf2f((unsigned short)(tA.y & 0xFFFFu)), bf2f((unsigned short)(tA.y >> 16)),
                        bf2f((unsigned short)(tB.x & 0xFFFFu)), bf2f((unsigned short)(tB.x >> 16)),
                        bf2f((unsigned short)(tB.y & 0xFFFFu)), bf2f((unsigned short)(tB.y >> 16)),
                        bf2f((unsigned short)(tC.x & 0xFFFFu)), bf2f((unsigned short)(tC.x >> 16)),
                        bf2f((unsigned short)(tC.y & 0xFFFFu)), bf2f((unsigned short)(tC.y >> 16))};
        float acc2 = 0.f;
        #pragma unroll
        for (int p = 0; p < 12; ++p) {
            float t = tt[p];
            float ez = __expf(-fmaf(t, qz, p0z));
            float eh = __expf(-2.f * fmaf(t, qh, p0h));
            float R = __builtin_amdgcn_rcpf((1.f + ez) * (1.f + eh));
            acc2 = fmaf(s_pr[p] * ez * (1.f - eh), R, acc2);
        }
        float h2 = fmaxf(acc2, 0.f);
        ((float*)&scr[wid][0])[lane] = h2;
        asm volatile("s_waitcnt lgkmcnt(0)" ::: "memory");

        // ---- h3 = relu(h2 . lw1 + lb1), split over halves ----
        float h3 = half ? 0.f : lb1v;
        const float4* hrow = &scr[wid][half * 8];
        #pragma unroll
        for (int c = 0; c < 8; ++c) {
            float4 hv = hrow[c];
            int jb = half * 32 + c * 4;
            h3 = fmaf(hv.x, s_lw1[(jb + 0) * 32 + ch], h3);
            h3 = fmaf(hv.y, s_lw1[(jb + 1) * 32 + ch], h3);
            h3 = fmaf(hv.z, s_lw1[(jb + 2) * 32 + ch], h3);
            h3 = fmaf(hv.w, s_lw1[(jb + 3) * 32 + ch], h3);
        }
        h3 += __shfl_xor(h3, 32, 64);
        h3 = fmaxf(h3, 0.f);

        // ---- out = h3 . lw2 + lb2 (lw2 in registers) ----
        float o = lb2v;
        #pragma unroll
        for (int i = 0; i < 8; ++i) {
            float h3k = __shfl(h3, q_ * 8 + i, 64);
            o = fmaf(h3k, wlw2[i], o);
        }
        o += __shfl_xor(o, 16, 64);
        o += __shfl_xor(o, 32, 64);
        if (lane < 12)
            __builtin_nontemporal_store(o, out + (size_t)node * 12 + lane);
    }
}

extern "C" void kernel_launch(void* const* d_in, const int* in_sizes, int n_in,
                              void* d_out, int out_size, void* d_ws, size_t ws_size,
                              hipStream_t stream) {
    const float* x1   = (const float*)d_in[0];
    const int*   eidx = (const int*)d_in[1];
    const float* W1   = (const float*)d_in[4];
    const float* b1   = (const float*)d_in[5];
    const float* Wl1  = (const float*)d_in[6];
    const float* bl1  = (const float*)d_in[7];
    const float* att1 = (const float*)d_in[8];
    const float* W2   = (const float*)d_in[9];
    const float* b2   = (const float*)d_in[10];
    const float* Wl2  = (const float*)d_in[11];
    const float* bl2  = (const float*)d_in[12];
    const float* att2 = (const float*)d_in[13];
    const float* lw1  = (const float*)d_in[14];
    const float* lb1  = (const float*)d_in[15];
    const float* lw2  = (const float*)d_in[16];
    const float* lb2  = (const float*)d_in[17];
    (void)n_in; (void)out_size; (void)ws_size;

    int N = in_sizes[0] / 24;
    int E = in_sizes[1] / 2;
    const int* srcp = eidx;
    const int* dstp = eidx + E;
    int nb = (N + 1023) / 1024;
    int n32 = N * 32;
    int ncb = (n32 / 4 + 255) / 256;        // cvt blocks
    int neb4 = ((E + 3) / 4 + 255) / 256;   // count/scatter blocks (4 edges/thread)

    char* ws = (char*)d_ws;
    size_t off = 0;
    auto alloc = [&](size_t bytes) -> char* {
        char* p = ws + off;
        off += (bytes + 511) & ~(size_t)511;
        return p;
    };
    int*            cnt    = (int*)alloc((size_t)N * 4);
    int*            rowptr = (int*)alloc((size_t)(N + 1) * 4);
    float*          dinv   = (float*)alloc((size_t)N * 4);
    int*            epos   = (int*)alloc((size_t)E * 4);
    unsigned*       cwp    = (unsigned*)alloc((size_t)E * 4);
    unsigned short* x1h    = (unsigned short*)alloc((size_t)n32 * 2);
    unsigned short* hbuf   = (unsigned short*)alloc((size_t)N * 32 * 2);
    unsigned short* atimeh = (unsigned short*)alloc((size_t)N * 12 * 2);
    float*          small  = (float*)alloc(4624 * 4);
    int*            bsum   = (int*)alloc((size_t)nb * 4);

    (void)hipMemsetAsync(cnt, 0, (size_t)N * 4, stream);
    prep_cvt_count<<<PREPB + ncb + neb4, 256, 0, stream>>>(
        x1, x1h, n32, ncb, dstp, cnt, epos, E,
        W1, b1, Wl1, bl1, att1, W2, b2, Wl2, bl2, att2, small);
    scan_blocksum<<<nb, 256, 0, stream>>>(cnt, dinv, bsum, N);
    scan_write<<<nb, 256, 0, stream>>>(cnt, bsum, nb, rowptr, N);
    scatter_edges<<<neb4, 256, 0, stream>>>(srcp, dstp, epos, dinv, rowptr, cwp, E);
    agg1_layer1<<<(N * 32 + 255) / 256, 256, 0, stream>>>(x1, x1h, rowptr, cwp, dinv, small, hbuf, atimeh, N);
    agg2_layer2<<<1024, 512, 0, stream>>>(hbuf, atimeh, rowptr, cwp, dinv, small,
                                          lw1, lb1, lw2, lb2, (float*)d_out, N);
}